// Round 12
// baseline (2822.750 us; speedup 1.0000x reference)
//
#include <hip/hip_runtime.h>

#define D_ 6
#define B_ 4
#define L_ 2048
#define E_ 1024
#define H_ 16
#define F_ 4096
#define BL_ (B_ * L_)
#define QKS 2048
#define EPS_ 1e-5f
// Q pre-scale: exp(s*0.125) == exp2(s * 0.125*log2(e)); folded into Wq/bq.
#define EXPSC 0.18033688011112042f
#define LOG2E 1.4426950408889634f
#define LOG2E_H (LOG2E / 16.0f)

typedef __bf16 bf16x8 __attribute__((ext_vector_type(8)));
typedef __bf16 bf16x4 __attribute__((ext_vector_type(4)));
typedef float f32x4 __attribute__((ext_vector_type(4)));

__device__ __forceinline__ float fexp2(float x) {
  return __builtin_amdgcn_exp2f(x);  // raw v_exp_f32 (args in safe range)
}

__device__ __forceinline__ void gload_lds16(const void* g, void* l) {
  __builtin_amdgcn_global_load_lds(
      (const __attribute__((address_space(1))) void*)g,
      (__attribute__((address_space(3))) void*)l, 16, 0, 0);
}

// 64x64 tile with 512 threads: 1 load/thread.  Source pre-swizzled
// (cu ^= row&7) so swizzled ds_read_b128 is conflict-free.
__device__ __forceinline__ void stage_tile64_512(__bf16* ldsb,
                                                 const __bf16* gbase, long ldg,
                                                 int tid) {
  int row = tid >> 3, cu = tid & 7;
  const __bf16* src = gbase + (long)row * ldg + ((cu ^ (row & 7)) << 3);
  gload_lds16(src, ldsb + (long)((tid & ~63) << 3));
}

// 128x64 tile (16KB) with 512 threads: 2 loads/thread.
__device__ __forceinline__ void stage_tile128_512(__bf16* ldsb,
                                                  const __bf16* gbase,
                                                  long ldg, int tid) {
#pragma unroll
  for (int j = 0; j < 2; ++j) {
    int unit = j * 512 + tid;
    int row = unit >> 3, cu = unit & 7;
    const __bf16* src = gbase + (long)row * ldg + ((cu ^ (row & 7)) << 3);
    gload_lds16(src, ldsb + (long)((j * 512 + (tid & ~63)) << 3));
  }
}

// swizzled fragment read from a linear [R][64] tile: row r_, k-slice kk
#define RD_FRAG(ldsb, r_, kk) \
  (*(const bf16x8*)&(ldsb)[((r_) * 8 + (((kk) * 4 + l4) ^ ((r_) & 7))) * 8])

// ---------------------------------------------------------------------------
// 256x256 8-phase GEMM.  C = A * B^T.  (unchanged from rounds 8-11)
// EPI: 0 = raw bf16 (split-K partial); 1 = +bias bf16; 2 = +bias relu bf16.
// ---------------------------------------------------------------------------
#define LDA_SUB(P, MH)                                                        \
  _Pragma("unroll") for (int mi = 0; mi < 4; ++mi)                            \
  _Pragma("unroll") for (int kk = 0; kk < 2; ++kk) {                          \
    int r_ = wr + (MH) * 64 + mi * 16 + l15;                                  \
    int cu_ = kk * 4 + l4;                                                    \
    aF[mi][kk] = *(const bf16x8*)&lds[P][0][(r_ * 8 + (cu_ ^ (r_ & 7))) * 8]; \
  }

#define LDB_SUB(P, BF, NH)                                                    \
  _Pragma("unroll") for (int ni = 0; ni < 2; ++ni)                            \
  _Pragma("unroll") for (int kk = 0; kk < 2; ++kk) {                          \
    int r_ = wc + (NH) * 32 + ni * 16 + l15;                                  \
    int cu_ = kk * 4 + l4;                                                    \
    BF[ni][kk] = *(const bf16x8*)&lds[P][1][(r_ * 8 + (cu_ ^ (r_ & 7))) * 8]; \
  }

#define MFMA_Q(AF, BF, MH, NH)                                                \
  _Pragma("unroll") for (int mi = 0; mi < 4; ++mi)                            \
  _Pragma("unroll") for (int ni = 0; ni < 2; ++ni)                            \
  _Pragma("unroll") for (int kk = 0; kk < 2; ++kk)                            \
    acc[(MH) * 4 + mi][(NH) * 2 + ni] =                                       \
        __builtin_amdgcn_mfma_f32_16x16x32_bf16(                              \
            AF[mi][kk], BF[ni][kk], acc[(MH) * 4 + mi][(NH) * 2 + ni], 0, 0, 0);

#define PHASE_PRE()                                                           \
  __builtin_amdgcn_s_barrier();                                               \
  asm volatile("s_waitcnt lgkmcnt(0)" ::: "memory");                          \
  __builtin_amdgcn_sched_barrier(0);                                          \
  __builtin_amdgcn_s_setprio(1)

#define PHASE_POST()                                                          \
  __builtin_amdgcn_s_setprio(0);                                              \
  __builtin_amdgcn_sched_barrier(0);                                          \
  __builtin_amdgcn_s_barrier()

#define STAGE_A(BUFI, HF, K0)                                                 \
  do {                                                                        \
    gload_lds16(sA[HF][0] + (K0),                                             \
                &lds[BUFI][0][((HF) * 1024 + wave * 64) * 8]);                \
    gload_lds16(sA[HF][1] + (K0),                                             \
                &lds[BUFI][0][((HF) * 1024 + 512 + wave * 64) * 8]);          \
  } while (0)

#define STAGE_B(BUFI, HF, K0)                                                 \
  do {                                                                        \
    gload_lds16(sB[HF][0] + (K0),                                             \
                &lds[BUFI][1][((HF) * 1024 + wave * 64) * 8]);                \
    gload_lds16(sB[HF][1] + (K0),                                             \
                &lds[BUFI][1][((HF) * 1024 + 512 + wave * 64) * 8]);          \
  } while (0)

template <int EPI>
__global__ __launch_bounds__(512, 2) void gemm8p(
    const __bf16* __restrict__ A, const __bf16* __restrict__ Bm,
    __bf16* __restrict__ Cb, const float* __restrict__ bias, int M, int N,
    int K, int lda, int ldb, int zk, long strA, long strB, long strC,
    long strCk) {
  __shared__ __bf16 lds[2][2][256 * 64];
  const int tid = threadIdx.x;
  const int wave = tid >> 6, lane = tid & 63;
  const int l15 = lane & 15, l4 = lane >> 4;
  const int z = blockIdx.y;
  const int kc = (zk == 2) ? (z & 1) : 0;
  const int bat = (zk == 2) ? (z >> 1) : z;
  const __bf16* Ab = A + (long)bat * strA + (long)kc * K;
  const __bf16* Bb = Bm + (long)bat * strB + (long)kc * K;
  const long coff = (long)bat * strC + (long)kc * strCk;

  const int nbx = N >> 8;
  const int nwg = (M >> 8) * nbx;
  const int orig = blockIdx.x;
  const int qq = nwg >> 3, rr = nwg & 7;
  const int xcd = orig & 7, lid = orig >> 3;
  const int wg = (xcd < rr ? xcd * (qq + 1) : rr * (qq + 1) + (xcd - rr) * qq) + lid;
  const int row0 = (wg / nbx) * 256, col0 = (wg % nbx) * 256;
  const int wr = (wave >> 2) * 128;
  const int wc = (wave & 3) * 64;

  const int rsel = tid >> 3;
  const int swz = ((lane & 7) ^ (rsel & 7)) << 3;
  const __bf16* sA[2][2];
  const __bf16* sB[2][2];
#pragma unroll
  for (int hf = 0; hf < 2; ++hf)
#pragma unroll
    for (int j = 0; j < 2; ++j) {
      sA[hf][j] = Ab + (long)(row0 + hf * 128 + j * 64 + rsel) * lda + swz;
      sB[hf][j] = Bb + (long)(col0 + hf * 128 + j * 64 + rsel) * ldb + swz;
    }

  const int NT = K >> 6;
  STAGE_A(0, 0, 0);
  STAGE_A(0, 1, 0);
  STAGE_B(0, 0, 0);
  STAGE_B(0, 1, 0);
  STAGE_A(1, 0, 64);
  STAGE_B(1, 0, 64);
  STAGE_A(1, 1, 64);
  asm volatile("s_waitcnt vmcnt(6)" ::: "memory");
  __builtin_amdgcn_s_barrier();

  f32x4 acc[8][4];
#pragma unroll
  for (int i = 0; i < 8; ++i)
#pragma unroll
    for (int j = 0; j < 4; ++j) acc[i][j] = (f32x4){0.f, 0.f, 0.f, 0.f};
  bf16x8 aF[4][2], b0F[2][2], b1F[2][2];

  for (int t = 0; t < NT; ++t) {
    const int p = t & 1;
    const int kA = (t + 1 < NT ? t + 1 : NT - 1) << 6;
    const int kB = (t + 2 < NT ? t + 2 : NT - 1) << 6;
    LDA_SUB(p, 0);
    LDB_SUB(p, b0F, 0);
    STAGE_B(p ^ 1, 1, kA);
    PHASE_PRE();
    MFMA_Q(aF, b0F, 0, 0);
    PHASE_POST();
    LDB_SUB(p, b1F, 1);
    PHASE_PRE();
    MFMA_Q(aF, b1F, 0, 1);
    PHASE_POST();
    LDA_SUB(p, 1);
    STAGE_B(p, 0, kB);
    PHASE_PRE();
    MFMA_Q(aF, b0F, 1, 0);
    PHASE_POST();
    STAGE_A(p, 0, kB);
    STAGE_A(p, 1, kB);
    __builtin_amdgcn_s_barrier();
    __builtin_amdgcn_sched_barrier(0);
    __builtin_amdgcn_s_setprio(1);
    MFMA_Q(aF, b1F, 1, 1);
    __builtin_amdgcn_s_setprio(0);
    __builtin_amdgcn_sched_barrier(0);
    asm volatile("s_waitcnt vmcnt(6)" ::: "memory");
    __builtin_amdgcn_s_barrier();
  }
  asm volatile("s_waitcnt vmcnt(0)" ::: "memory");

#pragma unroll
  for (int i = 0; i < 8; ++i) {
    int row = row0 + wr + (i >> 2) * 64 + (i & 3) * 16 + l4 * 4;
#pragma unroll
    for (int j = 0; j < 4; ++j) {
      int col = col0 + wc + (j >> 1) * 32 + (j & 1) * 16 + l15;
      float bval = 0.f;
      if constexpr (EPI == 1 || EPI == 2) bval = bias[col];
#pragma unroll
      for (int r = 0; r < 4; ++r) {
        long crow = row + r;
        float v = acc[i][j][r];
        if constexpr (EPI == 1 || EPI == 2) v += bval;
        if constexpr (EPI == 2) v = fmaxf(v, 0.f);
        Cb[coff + crow * N + col] = (__bf16)v;
      }
    }
  }
}

// ---------------------------------------------------------------------------
// Attention pass A (unchanged from r11): per (b,h,row) sum of exp2(s').
// Q frags direct global->reg (once per block); K streamed, vmcnt(1) dbuf.
// ---------------------------------------------------------------------------
__global__ __launch_bounds__(512, 4) void attn_stats_kernel(
    const __bf16* __restrict__ qk, float* __restrict__ sinv) {
  __shared__ __bf16 sK[2][64 * 64];
  const int tid = threadIdx.x, wave = tid >> 6, lane = tid & 63;
  const int l15 = lane & 15, l4 = lane >> 4;
  const int l0 = blockIdx.x * 128, h = blockIdx.y, b = blockIdx.z;
  const __bf16* Kb = qk + ((long)b * L_) * QKS + 1024 + h * 64;

  const __bf16* qp =
      qk + ((long)(b * L_ + l0 + wave * 16 + l15)) * QKS + h * 64 + l4 * 8;
  const bf16x8 aF0 = *(const bf16x8*)qp;
  const bf16x8 aF1 = *(const bf16x8*)(qp + 32);

  stage_tile64_512(sK[0], Kb, QKS, tid);
  asm volatile("s_waitcnt vmcnt(0)" ::: "memory");
  __builtin_amdgcn_s_barrier();

  float msum[4] = {0.f, 0.f, 0.f, 0.f};
  int p = 0;
  for (int m0 = 0; m0 < 32; ++m0) {
    const int mn = (m0 + 1 < 32) ? m0 + 1 : 31;
    stage_tile64_512(sK[p ^ 1], Kb + (long)mn * 64 * QKS, QKS, tid);
    asm volatile("s_waitcnt vmcnt(1)" ::: "memory");  // buf[p] resident
    __builtin_amdgcn_s_barrier();
#pragma unroll
    for (int ni = 0; ni < 4; ++ni) {
      const int rB = ni * 16 + l15;
      bf16x8 b0 = RD_FRAG(sK[p], rB, 0);
      bf16x8 b1 = RD_FRAG(sK[p], rB, 1);
      f32x4 s = (f32x4){0.f, 0.f, 0.f, 0.f};
      s = __builtin_amdgcn_mfma_f32_16x16x32_bf16(aF0, b0, s, 0, 0, 0);
      s = __builtin_amdgcn_mfma_f32_16x16x32_bf16(aF1, b1, s, 0, 0, 0);
#pragma unroll
      for (int r = 0; r < 4; ++r) msum[r] += fexp2(s[r]);
    }
    asm volatile("" ::: "memory");
    __builtin_amdgcn_s_barrier();
    p ^= 1;
  }
#pragma unroll
  for (int r = 0; r < 4; ++r) {
    float s = msum[r];
    for (int d = 1; d < 16; d <<= 1) s += __shfl_xor(s, d, 64);
    msum[r] = s;
  }
  if (l15 == 0) {
    long idx = ((long)(b * H_ + h)) * L_ + l0 + wave * 16 + l4 * 4;
    f32x4 o = {1.0f / msum[0], 1.0f / msum[1], 1.0f / msum[2], 1.0f / msum[3]};
    *(f32x4*)&sinv[idx] = o;
  }
}

// ---------------------------------------------------------------------------
// Attention pass B v2: 128x128 tile, 512 threads.  Q global->reg PREFETCHED
// one h ahead via explicit double register sets (loop unrolled x2 -> static
// names, no copies).  K in 32KB LDS dbuf (r9's working prefetch).  Per-iter
// issues = Q(4)+K(2) -> vmcnt(6) retires exactly prev iter's {Q,K,iv}.
// iv loaded post-barrier (auto-waited; ~8 MFMA of slack).
// ---------------------------------------------------------------------------
__global__ void attn_probs_kernel(
    const __bf16* __restrict__ qk, const float* __restrict__ sinv,
    const float* __restrict__ relTab, __bf16* __restrict__ P,
    float* __restrict__ rowsumT) {
  __shared__ __bf16 sKl[2][128 * 64];
  const int tid = threadIdx.x, wave = tid >> 6, lane = tid & 63;
  const int l15 = lane & 15, l4 = lane >> 4;
  const int m0 = blockIdx.x * 128, l0 = blockIdx.y * 128, b = blockIdx.z;
  const int wr2 = wave & 3, wc2 = wave >> 2;
  const __bf16* Kb = qk + ((long)(b * L_ + m0)) * QKS + 1024;

  const int rowbase = l0 + wr2 * 32 + l4 * 4;
  // per-lane Q fragment base pointers (row-halves 0/+16 of this wave's 32)
  const __bf16* qp0 =
      qk + ((long)(b * L_ + l0 + wr2 * 32 + l15)) * QKS + l4 * 8;
  const __bf16* qp1 = qp0 + 16 * QKS;

  float wacc[4][8];  // [ni][fi*4+r]
#pragma unroll
  for (int i = 0; i < 4; ++i)
#pragma unroll
    for (int j = 0; j < 8; ++j) wacc[i][j] = 0.f;

  bf16x8 qA[2][2], qB[2][2];
  // prologue: Q[0] (4 loads) + stage K[0] (2 loads) -> 6 outstanding
  qA[0][0] = *(const bf16x8*)(qp0);
  qA[0][1] = *(const bf16x8*)(qp0 + 32);
  qA[1][0] = *(const bf16x8*)(qp1);
  qA[1][1] = *(const bf16x8*)(qp1 + 32);
  stage_tile128_512(sKl[0], Kb, QKS, tid);

  auto BODY = [&](bf16x8(&qc)[2][2], bf16x8(&qn)[2][2], int h, int p) {
    const int hn = (h + 1 < H_) ? h + 1 : H_ - 1;
    // prefetch Q[h+1] into the OTHER register set + stage K[h+1]
    qn[0][0] = *(const bf16x8*)(qp0 + hn * 64);
    qn[0][1] = *(const bf16x8*)(qp0 + hn * 64 + 32);
    qn[1][0] = *(const bf16x8*)(qp1 + hn * 64);
    qn[1][1] = *(const bf16x8*)(qp1 + hn * 64 + 32);
    stage_tile128_512(sKl[p ^ 1], Kb + hn * 64, QKS, tid);
    // retire everything older than this iter's 6 issues: prev {Q,K,iv}
    asm volatile("s_waitcnt vmcnt(6)" ::: "memory");
    __builtin_amdgcn_s_barrier();
    const float* svh = &sinv[((long)(b * H_ + h)) * L_];
    f32x4 iv0 = *(const f32x4*)&svh[rowbase];
    f32x4 iv1 = *(const f32x4*)&svh[rowbase + 16];
#pragma unroll
    for (int ni = 0; ni < 4; ++ni) {
      const int rB = wc2 * 64 + ni * 16 + l15;
      bf16x8 b0 = RD_FRAG(sKl[p], rB, 0);
      bf16x8 b1 = RD_FRAG(sKl[p], rB, 1);
#pragma unroll
      for (int fi = 0; fi < 2; ++fi) {
        f32x4 s = (f32x4){0.f, 0.f, 0.f, 0.f};
        s = __builtin_amdgcn_mfma_f32_16x16x32_bf16(qc[fi][0], b0, s, 0, 0, 0);
        s = __builtin_amdgcn_mfma_f32_16x16x32_bf16(qc[fi][1], b1, s, 0, 0, 0);
#pragma unroll
        for (int r = 0; r < 4; ++r)
          wacc[ni][fi * 4 + r] += fexp2(s[r]) * (fi ? iv1[r] : iv0[r]);
      }
    }
    asm volatile("" ::: "memory");
    __builtin_amdgcn_s_barrier();  // all reads of sKl[p] done
  };

  for (int hh = 0; hh < H_; hh += 2) {
    BODY(qA, qB, hh, 0);
    BODY(qB, qA, hh + 1, 1);
  }

  float rowpart[2][4] = {{0.f, 0.f, 0.f, 0.f}, {0.f, 0.f, 0.f, 0.f}};
#pragma unroll
  for (int ni = 0; ni < 4; ++ni) {
#pragma unroll
    for (int fi = 0; fi < 2; ++fi) {
#pragma unroll
      for (int r = 0; r < 4; ++r) {
        int row = rowbase + fi * 16 + r;
        int col = m0 + wc2 * 64 + ni * 16 + l15;
        float relL = relTab[row - col + 2048];  // already * log2e
        float pv = fexp2(fmaf(wacc[ni][fi * 4 + r], LOG2E_H, relL));
        P[((long)b * L_ + row) * L_ + col] = (__bf16)pv;
        rowpart[fi][r] += pv;
      }
    }
  }
#pragma unroll
  for (int fi = 0; fi < 2; ++fi) {
#pragma unroll
    for (int r = 0; r < 4; ++r) {
      float s = rowpart[fi][r];
      s += __shfl_xor(s, 1, 16);
      s += __shfl_xor(s, 2, 16);
      s += __shfl_xor(s, 4, 16);
      s += __shfl_xor(s, 8, 16);
      if (l15 == 0) {
        int row = rowbase + fi * 16 + r;
        rowsumT[((long)b * L_ + row) * 32 + (m0 >> 6) + wc2] = s;
      }
    }
  }
}

// ---------------------------------------------------------------------------
__device__ __forceinline__ void wave_reduce2(float& a, float& b) {
#pragma unroll
  for (int d = 1; d < 64; d <<= 1) {
    a += __shfl_xor(a, d, 64);
    b += __shfl_xor(b, d, 64);
  }
}

// h1 = LN(h + rinv*(p0+p1)); h2 = LN(h1).  h2 written in bf16 only.
__global__ __launch_bounds__(256, 4) void ln12_kernel(
    const float* __restrict__ hin, const __bf16* __restrict__ p0,
    const __bf16* __restrict__ p1, const float* __restrict__ rowsumT,
    const float* __restrict__ w1, const float* __restrict__ b1,
    const float* __restrict__ w2, const float* __restrict__ b2,
    __bf16* __restrict__ h2b) {
  __shared__ float sh[9];
  const int tid = threadIdx.x;
  const long row = blockIdx.x;
  const long base = row * E_ + tid * 4;
  if (tid < 32) {
    float s = rowsumT[row * 32 + tid];
#pragma unroll
    for (int d = 1; d < 32; d <<= 1) s += __shfl_xor(s, d, 32);
    if (tid == 0) sh[8] = s;
  }
  f32x4 hv = *(const f32x4*)&hin[base];
  bf16x4 p0v = *(const bf16x4*)&p0[base];
  bf16x4 p1v = *(const bf16x4*)&p1[base];
  __syncthreads();
  const float rinv = 1.0f / sh[8];
  float y[4];
  float s1 = 0.f, s2 = 0.f;
#pragma unroll
  for (int j = 0; j < 4; ++j) {
    y[j] = hv[j] + rinv * ((float)p0v[j] + (float)p1v[j]);
    s1 += y[j];
    s2 += y[j] * y[j];
  }
  wave_reduce2(s1, s2);
  if ((tid & 63) == 0) { sh[(tid >> 6) * 2] = s1; sh[(tid >> 6) * 2 + 1] = s2; }
  __syncthreads();
  s1 = sh[0] + sh[2] + sh[4] + sh[6];
  s2 = sh[1] + sh[3] + sh[5] + sh[7];
  float mean = s1 * (1.f / E_);
  float var = s2 * (1.f / E_) - mean * mean;
  float rs = rsqrtf(var + EPS_);
  f32x4 wv = *(const f32x4*)&w1[tid * 4];
  f32x4 bv = *(const f32x4*)&b1[tid * 4];
  float h1[4];
  s1 = 0.f; s2 = 0.f;
#pragma unroll
  for (int j = 0; j < 4; ++j) {
    h1[j] = (y[j] - mean) * rs * wv[j] + bv[j];
    s1 += h1[j];
    s2 += h1[j] * h1[j];
  }
  __syncthreads();
  wave_reduce2(s1, s2);
  if ((tid & 63) == 0) { sh[(tid >> 6) * 2] = s1; sh[(tid >> 6) * 2 + 1] = s2; }
  __syncthreads();
  s1 = sh[0] + sh[2] + sh[4] + sh[6];
  s2 = sh[1] + sh[3] + sh[5] + sh[7];
  mean = s1 * (1.f / E_);
  var = s2 * (1.f / E_) - mean * mean;
  rs = rsqrtf(var + EPS_);
  wv = *(const f32x4*)&w2[tid * 4];
  bv = *(const f32x4*)&b2[tid * 4];
  bf16x4 ob;
#pragma unroll
  for (int j = 0; j < 4; ++j)
    ob[j] = (__bf16)((h1[j] - mean) * rs * wv[j] + bv[j]);
  *(bf16x4*)&h2b[base] = ob;
}

// out = LN(h2 + (p0+p1+b2)).  h2 read as bf16; outb overwrites after read.
__global__ __launch_bounds__(256, 4) void ln3_kernel(
    const __bf16* __restrict__ h2b_in, const __bf16* __restrict__ p0,
    const __bf16* __restrict__ p1, const float* __restrict__ bias2,
    const float* __restrict__ w3, const float* __restrict__ b3,
    float* __restrict__ outf, __bf16* __restrict__ outb) {
  __shared__ float sh[8];
  const int tid = threadIdx.x;
  const long row = blockIdx.x;
  const long base = row * E_ + tid * 4;
  bf16x4 hv = *(const bf16x4*)&h2b_in[base];
  bf16x4 p0v = *(const bf16x4*)&p0[base];
  bf16x4 p1v = *(const bf16x4*)&p1[base];
  f32x4 b2v = *(const f32x4*)&bias2[tid * 4];
  float y[4];
  float s1 = 0.f, s2 = 0.f;
#pragma unroll
  for (int j = 0; j < 4; ++j) {
    y[j] = (float)hv[j] + (float)p0v[j] + (float)p1v[j] + b2v[j];
    s1 += y[j];
    s2 += y[j] * y[j];
  }
  wave_reduce2(s1, s2);
  if ((tid & 63) == 0) { sh[(tid >> 6) * 2] = s1; sh[(tid >> 6) * 2 + 1] = s2; }
  __syncthreads();
  s1 = sh[0] + sh[2] + sh[4] + sh[6];
  s2 = sh[1] + sh[3] + sh[5] + sh[7];
  float mean = s1 * (1.f / E_);
  float var = s2 * (1.f / E_) - mean * mean;
  float rs = rsqrtf(var + EPS_);
  f32x4 wv = *(const f32x4*)&w3[tid * 4];
  f32x4 bv = *(const f32x4*)&b3[tid * 4];
  f32x4 o;
  bf16x4 ob;
#pragma unroll
  for (int j = 0; j < 4; ++j) {
    float v = (y[j] - mean) * rs * wv[j] + bv[j];
    o[j] = v;
    ob[j] = (__bf16)v;
  }
  *(f32x4*)&outf[base] = o;
  *(bf16x4*)&outb[base] = ob;
}

// ---------------------------------------------------------------------------
__global__ __launch_bounds__(256, 4) void transpose_kernel(
    const __bf16* __restrict__ X, __bf16* __restrict__ XT) {
  __shared__ __bf16 t[64 * 66];
  const int l0 = blockIdx.x * 64, e0 = blockIdx.y * 64, b = blockIdx.z;
  const int tid = threadIdx.x;
#pragma unroll
  for (int r = 0; r < 2; ++r) {
    int c = tid + 256 * r;
    int rw = c >> 3, c8 = (c & 7) * 8;
    *(bf16x8*)&t[rw * 66 + c8] =
        *(const bf16x8*)&X[((long)(b * L_) + l0 + rw) * E_ + e0 + c8];
  }
  __syncthreads();
#pragma unroll
  for (int r = 0; r < 2; ++r) {
    int c = tid + 256 * r;
    int er = c >> 3, l8 = (c & 7) * 8;
    bf16x8 v;
#pragma unroll
    for (int j = 0; j < 8; ++j) v[j] = t[(l8 + j) * 66 + er];
    *(bf16x8*)&XT[((long)(b * E_) + e0 + er) * L_ + l0 + l8] = v;
  }
}

__global__ __launch_bounds__(256, 4) void f32_to_bf16_kernel(
    const float* __restrict__ x, __bf16* __restrict__ y) {
  long i = ((long)blockIdx.x * 256 + threadIdx.x) * 4;
  f32x4 v = *(const f32x4*)&x[i];
  bf16x4 o;
#pragma unroll
  for (int j = 0; j < 4; ++j) o[j] = (__bf16)v[j];
  *(bf16x4*)&y[i] = o;
}

// fused [D][2048][1024] Wqk (rows 0-1023 = Wq * EXPSC, 1024-2047 = Wk), bf16
__global__ __launch_bounds__(256, 4) void build_wqk_kernel(
    const float* __restrict__ Wq, const float* __restrict__ Wk,
    __bf16* __restrict__ out) {
  long i = ((long)blockIdx.x * 256 + threadIdx.x) * 4;
  long d = i >> 21;
  long rem = i & ((1L << 21) - 1);
  long row = rem >> 10, col = rem & 1023;
  const bool isQ = (row < 1024);
  const float* src = isQ ? &Wq[(d << 20) + (row << 10) + col]
                         : &Wk[(d << 20) + ((row - 1024) << 10) + col];
  const float sc = isQ ? EXPSC : 1.0f;
  f32x4 v = *(const f32x4*)src;
  bf16x4 o;
#pragma unroll
  for (int j = 0; j < 4; ++j) o[j] = (__bf16)(v[j] * sc);
  *(bf16x4*)&out[i] = o;
}

__global__ __launch_bounds__(256, 4) void build_bqk_kernel(
    const float* __restrict__ bq, const float* __restrict__ bk,
    float* __restrict__ out) {
  int i = blockIdx.x * 256 + threadIdx.x;  // D*2048
  int d = i >> 11, c = i & 2047;
  out[i] = (c < 1024) ? bq[d * 1024 + c] * EXPSC : bk[d * 1024 + c - 1024];
}

// relTab[d+2048] = exp(-|d|/16) * log2(e)
__global__ __launch_bounds__(256, 4) void build_rel_kernel(
    float* __restrict__ relTab) {
  int i = blockIdx.x * 256 + threadIdx.x;  // 4096
  relTab[i] = __expf(-fabsf((float)(i - 2048)) * (1.0f / 16.0f)) * LOG2E;
}

// ---------------------------------------------------------------------------
extern "C" void kernel_launch(void* const* d_in, const int* in_sizes, int n_in,
                              void* d_out, int out_size, void* d_ws,
                              size_t ws_size, hipStream_t stream) {
  const float* x = (const float*)d_in[0];
  const float* Wq = (const float*)d_in[1];
  const float* Wk = (const float*)d_in[2];
  const float* bq = (const float*)d_in[3];
  const float* bk = (const float*)d_in[4];
  const float* l1w = (const float*)d_in[5];
  const float* l1b = (const float*)d_in[6];
  const float* l2w = (const float*)d_in[7];
  const float* l2b = (const float*)d_in[8];
  const float* l3w = (const float*)d_in[9];
  const float* l3b = (const float*)d_in[10];
  const float* W1 = (const float*)d_in[11];
  const float* b1 = (const float*)d_in[12];
  const float* W2 = (const float*)d_in[13];
  const float* b2 = (const float*)d_in[14];

  char* p = (char*)d_ws;
  auto take = [&](size_t bytes) -> char* {
    char* r = p;
    p += (bytes + 255) & ~(size_t)255;
    return r;
  };
  __bf16* wqk_bf = (__bf16*)take((size_t)D_ * 2048 * 1024 * 2);
  __bf16* w1_bf = (__bf16*)take((size_t)D_ * F_ * E_ * 2);
  __bf16* w2_bf = (__bf16*)take((size_t)D_ * E_ * F_ * 2);
  __bf16* h_bf = (__bf16*)take((size_t)BL_ * E_ * 2);
  __bf16* hT = (__bf16*)take((size_t)BL_ * E_ * 2);
  __bf16* qk_bf = (__bf16*)take((size_t)BL_ * QKS * 2);     // union with ffmid
  __bf16* Pbuf = (__bf16*)take((size_t)B_ * L_ * L_ * 2);   // union with ffmid
  __bf16* ffmid = qk_bf;  // [BL][F] bf16 == qk+P exactly
  float* bqk = (float*)take((size_t)D_ * 2048 * 4);
  float* relTab = (float*)take((size_t)4096 * 4);
  float* sinv = (float*)take((size_t)B_ * H_ * L_ * 4);
  float* rowsumT = (float*)take((size_t)BL_ * 32 * 4);
  __bf16* partB = (__bf16*)take((size_t)2 * BL_ * E_ * 2);  // bf16 partials
  __bf16* part0 = partB;
  __bf16* part1 = partB + (size_t)BL_ * E_;
  float* hbuf = (float*)take((size_t)BL_ * E_ * 4);

  // --- setup ---
  build_wqk_kernel<<<D_ * 2048 * 1024 / 1024, 256, 0, stream>>>(Wq, Wk, wqk_bf);
  build_bqk_kernel<<<D_ * 2048 / 256, 256, 0, stream>>>(bq, bk, bqk);
  build_rel_kernel<<<16, 256, 0, stream>>>(relTab);
  f32_to_bf16_kernel<<<D_ * F_ * E_ / 1024, 256, 0, stream>>>(W1, w1_bf);
  f32_to_bf16_kernel<<<D_ * E_ * F_ / 1024, 256, 0, stream>>>(W2, w2_bf);
  f32_to_bf16_kernel<<<BL_ * E_ / 1024, 256, 0, stream>>>(x, h_bf);
  transpose_kernel<<<dim3(L_ / 64, E_ / 64, B_), 256, 0, stream>>>(h_bf, hT);

  const float* h_in = x;
  for (int d = 0; d < D_; ++d) {
    // fused QK projection: [BL][2048] = h @ [Wq*c;Wk]^T + [bq*c;bk]  (256 wgs)
    gemm8p<1><<<dim3(256, 1), 512, 0, stream>>>(
        h_bf, wqk_bf + (size_t)d * 2048 * 1024, qk_bf, bqk + d * 2048, BL_,
        2048, E_, E_, E_, 1, 0, 0, 0, 0);
    attn_stats_kernel<<<dim3(L_ / 128, H_, B_), 512, 0, stream>>>(qk_bf, sinv);
    attn_probs_kernel<<<dim3(L_ / 128, L_ / 128, B_), 512, 0, stream>>>(
        qk_bf, sinv, relTab, Pbuf, rowsumT);
    // sa-partials = P @ h  (4 batches x split-K2 = 8 z -> 256 wgs, bf16 out)
    gemm8p<0><<<dim3(32, 8), 512, 0, stream>>>(
        Pbuf, hT, partB, nullptr, L_, E_, L_ / 2, L_, L_, 2, (long)L_ * L_,
        (long)E_ * L_, (long)L_ * E_, (long)BL_ * E_);
    // h2 (bf16) -> h_bf
    ln12_kernel<<<BL_, 256, 0, stream>>>(h_in, part0, part1, rowsumT,
                                         l1w + d * E_, l1b + d * E_,
                                         l2w + d * E_, l2b + d * E_, h_bf);
    // FFN1 (512 wgs)
    gemm8p<2><<<dim3(512, 1), 512, 0, stream>>>(
        h_bf, w1_bf + (size_t)d * F_ * E_, ffmid, b1 + d * F_, BL_, F_, E_,
        E_, E_, 1, 0, 0, 0, 0);
    // FFN2 partials (split-K2 -> 256 wgs, bf16 out)
    gemm8p<0><<<dim3(128, 2), 512, 0, stream>>>(
        ffmid, w2_bf + (size_t)d * E_ * F_, partB, nullptr, BL_, E_, F_ / 2,
        F_, F_, 2, 0, 0, 0, (long)BL_ * E_);
    float* outp = (d == D_ - 1) ? (float*)d_out : hbuf;
    ln3_kernel<<<BL_, 256, 0, stream>>>(h_bf, part0, part1, b2 + d * E_,
                                        l3w + d * E_, l3b + d * E_, outp,
                                        h_bf);
    if (d < D_ - 1) {
      transpose_kernel<<<dim3(L_ / 64, E_ / 64, B_), 256, 0, stream>>>(h_bf, hT);
      h_in = hbuf;
    }
  }
}

// Round 13
// 2613.340 us; speedup vs baseline: 1.0801x; 1.0801x over previous
//
#include <hip/hip_runtime.h>

#define D_ 6
#define B_ 4
#define L_ 2048
#define E_ 1024
#define H_ 16
#define F_ 4096
#define BL_ (B_ * L_)
#define QKS 2048
#define EPS_ 1e-5f
// Q pre-scale: exp(s*0.125) == exp2(s * 0.125*log2(e)); folded into Wq/bq.
#define EXPSC 0.18033688011112042f
#define LOG2E 1.4426950408889634f
#define LOG2E_H (LOG2E / 16.0f)

typedef __bf16 bf16x8 __attribute__((ext_vector_type(8)));
typedef __bf16 bf16x4 __attribute__((ext_vector_type(4)));
typedef float f32x4 __attribute__((ext_vector_type(4)));

__device__ __forceinline__ float fexp2(float x) {
  return __builtin_amdgcn_exp2f(x);  // raw v_exp_f32 (args in safe range)
}

__device__ __forceinline__ void gload_lds16(const void* g, void* l) {
  __builtin_amdgcn_global_load_lds(
      (const __attribute__((address_space(1))) void*)g,
      (__attribute__((address_space(3))) void*)l, 16, 0, 0);
}

// 64x64 tile with 512 threads: 1 load/thread.  Source pre-swizzled
// (cu ^= row&7) so swizzled ds_read_b128 is conflict-free.
__device__ __forceinline__ void stage_tile64_512(__bf16* ldsb,
                                                 const __bf16* gbase, long ldg,
                                                 int tid) {
  int row = tid >> 3, cu = tid & 7;
  const __bf16* src = gbase + (long)row * ldg + ((cu ^ (row & 7)) << 3);
  gload_lds16(src, ldsb + (long)((tid & ~63) << 3));
}

// 128x64 tile (16KB) with 512 threads: 2 loads/thread.
__device__ __forceinline__ void stage_tile128_512(__bf16* ldsb,
                                                  const __bf16* gbase,
                                                  long ldg, int tid) {
#pragma unroll
  for (int j = 0; j < 2; ++j) {
    int unit = j * 512 + tid;
    int row = unit >> 3, cu = unit & 7;
    const __bf16* src = gbase + (long)row * ldg + ((cu ^ (row & 7)) << 3);
    gload_lds16(src, ldsb + (long)((j * 512 + (tid & ~63)) << 3));
  }
}

// swizzled fragment read from a linear [R][64] tile: row r_, k-slice kk
#define RD_FRAG(ldsb, r_, kk) \
  (*(const bf16x8*)&(ldsb)[((r_) * 8 + (((kk) * 4 + l4) ^ ((r_) & 7))) * 8])

// ---------------------------------------------------------------------------
// 256x256 8-phase GEMM.  C = A * B^T.  (unchanged from rounds 8-12)
// EPI: 0 = raw bf16 (split-K partial); 1 = +bias bf16; 2 = +bias relu bf16.
// ---------------------------------------------------------------------------
#define LDA_SUB(P, MH)                                                        \
  _Pragma("unroll") for (int mi = 0; mi < 4; ++mi)                            \
  _Pragma("unroll") for (int kk = 0; kk < 2; ++kk) {                          \
    int r_ = wr + (MH) * 64 + mi * 16 + l15;                                  \
    int cu_ = kk * 4 + l4;                                                    \
    aF[mi][kk] = *(const bf16x8*)&lds[P][0][(r_ * 8 + (cu_ ^ (r_ & 7))) * 8]; \
  }

#define LDB_SUB(P, BF, NH)                                                    \
  _Pragma("unroll") for (int ni = 0; ni < 2; ++ni)                            \
  _Pragma("unroll") for (int kk = 0; kk < 2; ++kk) {                          \
    int r_ = wc + (NH) * 32 + ni * 16 + l15;                                  \
    int cu_ = kk * 4 + l4;                                                    \
    BF[ni][kk] = *(const bf16x8*)&lds[P][1][(r_ * 8 + (cu_ ^ (r_ & 7))) * 8]; \
  }

#define MFMA_Q(AF, BF, MH, NH)                                                \
  _Pragma("unroll") for (int mi = 0; mi < 4; ++mi)                            \
  _Pragma("unroll") for (int ni = 0; ni < 2; ++ni)                            \
  _Pragma("unroll") for (int kk = 0; kk < 2; ++kk)                            \
    acc[(MH) * 4 + mi][(NH) * 2 + ni] =                                       \
        __builtin_amdgcn_mfma_f32_16x16x32_bf16(                              \
            AF[mi][kk], BF[ni][kk], acc[(MH) * 4 + mi][(NH) * 2 + ni], 0, 0, 0);

#define PHASE_PRE()                                                           \
  __builtin_amdgcn_s_barrier();                                               \
  asm volatile("s_waitcnt lgkmcnt(0)" ::: "memory");                          \
  __builtin_amdgcn_sched_barrier(0);                                          \
  __builtin_amdgcn_s_setprio(1)

#define PHASE_POST()                                                          \
  __builtin_amdgcn_s_setprio(0);                                              \
  __builtin_amdgcn_sched_barrier(0);                                          \
  __builtin_amdgcn_s_barrier()

#define STAGE_A(BUFI, HF, K0)                                                 \
  do {                                                                        \
    gload_lds16(sA[HF][0] + (K0),                                             \
                &lds[BUFI][0][((HF) * 1024 + wave * 64) * 8]);                \
    gload_lds16(sA[HF][1] + (K0),                                             \
                &lds[BUFI][0][((HF) * 1024 + 512 + wave * 64) * 8]);          \
  } while (0)

#define STAGE_B(BUFI, HF, K0)                                                 \
  do {                                                                        \
    gload_lds16(sB[HF][0] + (K0),                                             \
                &lds[BUFI][1][((HF) * 1024 + wave * 64) * 8]);                \
    gload_lds16(sB[HF][1] + (K0),                                             \
                &lds[BUFI][1][((HF) * 1024 + 512 + wave * 64) * 8]);          \
  } while (0)

template <int EPI>
__global__ __launch_bounds__(512, 2) void gemm8p(
    const __bf16* __restrict__ A, const __bf16* __restrict__ Bm,
    __bf16* __restrict__ Cb, const float* __restrict__ bias, int M, int N,
    int K, int lda, int ldb, int zk, long strA, long strB, long strC,
    long strCk) {
  __shared__ __bf16 lds[2][2][256 * 64];
  const int tid = threadIdx.x;
  const int wave = tid >> 6, lane = tid & 63;
  const int l15 = lane & 15, l4 = lane >> 4;
  const int z = blockIdx.y;
  const int kc = (zk == 2) ? (z & 1) : 0;
  const int bat = (zk == 2) ? (z >> 1) : z;
  const __bf16* Ab = A + (long)bat * strA + (long)kc * K;
  const __bf16* Bb = Bm + (long)bat * strB + (long)kc * K;
  const long coff = (long)bat * strC + (long)kc * strCk;

  const int nbx = N >> 8;
  const int nwg = (M >> 8) * nbx;
  const int orig = blockIdx.x;
  const int qq = nwg >> 3, rr = nwg & 7;
  const int xcd = orig & 7, lid = orig >> 3;
  const int wg = (xcd < rr ? xcd * (qq + 1) : rr * (qq + 1) + (xcd - rr) * qq) + lid;
  const int row0 = (wg / nbx) * 256, col0 = (wg % nbx) * 256;
  const int wr = (wave >> 2) * 128;
  const int wc = (wave & 3) * 64;

  const int rsel = tid >> 3;
  const int swz = ((lane & 7) ^ (rsel & 7)) << 3;
  const __bf16* sA[2][2];
  const __bf16* sB[2][2];
#pragma unroll
  for (int hf = 0; hf < 2; ++hf)
#pragma unroll
    for (int j = 0; j < 2; ++j) {
      sA[hf][j] = Ab + (long)(row0 + hf * 128 + j * 64 + rsel) * lda + swz;
      sB[hf][j] = Bb + (long)(col0 + hf * 128 + j * 64 + rsel) * ldb + swz;
    }

  const int NT = K >> 6;
  STAGE_A(0, 0, 0);
  STAGE_A(0, 1, 0);
  STAGE_B(0, 0, 0);
  STAGE_B(0, 1, 0);
  STAGE_A(1, 0, 64);
  STAGE_B(1, 0, 64);
  STAGE_A(1, 1, 64);
  asm volatile("s_waitcnt vmcnt(6)" ::: "memory");
  __builtin_amdgcn_s_barrier();

  f32x4 acc[8][4];
#pragma unroll
  for (int i = 0; i < 8; ++i)
#pragma unroll
    for (int j = 0; j < 4; ++j) acc[i][j] = (f32x4){0.f, 0.f, 0.f, 0.f};
  bf16x8 aF[4][2], b0F[2][2], b1F[2][2];

  for (int t = 0; t < NT; ++t) {
    const int p = t & 1;
    const int kA = (t + 1 < NT ? t + 1 : NT - 1) << 6;
    const int kB = (t + 2 < NT ? t + 2 : NT - 1) << 6;
    LDA_SUB(p, 0);
    LDB_SUB(p, b0F, 0);
    STAGE_B(p ^ 1, 1, kA);
    PHASE_PRE();
    MFMA_Q(aF, b0F, 0, 0);
    PHASE_POST();
    LDB_SUB(p, b1F, 1);
    PHASE_PRE();
    MFMA_Q(aF, b1F, 0, 1);
    PHASE_POST();
    LDA_SUB(p, 1);
    STAGE_B(p, 0, kB);
    PHASE_PRE();
    MFMA_Q(aF, b0F, 1, 0);
    PHASE_POST();
    STAGE_A(p, 0, kB);
    STAGE_A(p, 1, kB);
    __builtin_amdgcn_s_barrier();
    __builtin_amdgcn_sched_barrier(0);
    __builtin_amdgcn_s_setprio(1);
    MFMA_Q(aF, b1F, 1, 1);
    __builtin_amdgcn_s_setprio(0);
    __builtin_amdgcn_sched_barrier(0);
    asm volatile("s_waitcnt vmcnt(6)" ::: "memory");
    __builtin_amdgcn_s_barrier();
  }
  asm volatile("s_waitcnt vmcnt(0)" ::: "memory");

#pragma unroll
  for (int i = 0; i < 8; ++i) {
    int row = row0 + wr + (i >> 2) * 64 + (i & 3) * 16 + l4 * 4;
#pragma unroll
    for (int j = 0; j < 4; ++j) {
      int col = col0 + wc + (j >> 1) * 32 + (j & 1) * 16 + l15;
      float bval = 0.f;
      if constexpr (EPI == 1 || EPI == 2) bval = bias[col];
#pragma unroll
      for (int r = 0; r < 4; ++r) {
        long crow = row + r;
        float v = acc[i][j][r];
        if constexpr (EPI == 1 || EPI == 2) v += bval;
        if constexpr (EPI == 2) v = fmaxf(v, 0.f);
        Cb[coff + crow * N + col] = (__bf16)v;
      }
    }
  }
}

// ---------------------------------------------------------------------------
// Attention pass A (unchanged from r11): per (b,h,row) sum of exp2(s').
// Q frags direct global->reg (once per block); K streamed, vmcnt(1) dbuf.
// ---------------------------------------------------------------------------
__global__ __launch_bounds__(512, 4) void attn_stats_kernel(
    const __bf16* __restrict__ qk, float* __restrict__ sinv) {
  __shared__ __bf16 sK[2][64 * 64];
  const int tid = threadIdx.x, wave = tid >> 6, lane = tid & 63;
  const int l15 = lane & 15, l4 = lane >> 4;
  const int l0 = blockIdx.x * 128, h = blockIdx.y, b = blockIdx.z;
  const __bf16* Kb = qk + ((long)b * L_) * QKS + 1024 + h * 64;

  const __bf16* qp =
      qk + ((long)(b * L_ + l0 + wave * 16 + l15)) * QKS + h * 64 + l4 * 8;
  const bf16x8 aF0 = *(const bf16x8*)qp;
  const bf16x8 aF1 = *(const bf16x8*)(qp + 32);

  stage_tile64_512(sK[0], Kb, QKS, tid);
  asm volatile("s_waitcnt vmcnt(0)" ::: "memory");
  __builtin_amdgcn_s_barrier();

  float msum[4] = {0.f, 0.f, 0.f, 0.f};
  int p = 0;
  for (int m0 = 0; m0 < 32; ++m0) {
    const int mn = (m0 + 1 < 32) ? m0 + 1 : 31;
    stage_tile64_512(sK[p ^ 1], Kb + (long)mn * 64 * QKS, QKS, tid);
    asm volatile("s_waitcnt vmcnt(1)" ::: "memory");  // buf[p] resident
    __builtin_amdgcn_s_barrier();
#pragma unroll
    for (int ni = 0; ni < 4; ++ni) {
      const int rB = ni * 16 + l15;
      bf16x8 b0 = RD_FRAG(sK[p], rB, 0);
      bf16x8 b1 = RD_FRAG(sK[p], rB, 1);
      f32x4 s = (f32x4){0.f, 0.f, 0.f, 0.f};
      s = __builtin_amdgcn_mfma_f32_16x16x32_bf16(aF0, b0, s, 0, 0, 0);
      s = __builtin_amdgcn_mfma_f32_16x16x32_bf16(aF1, b1, s, 0, 0, 0);
#pragma unroll
      for (int r = 0; r < 4; ++r) msum[r] += fexp2(s[r]);
    }
    asm volatile("" ::: "memory");
    __builtin_amdgcn_s_barrier();
    p ^= 1;
  }
#pragma unroll
  for (int r = 0; r < 4; ++r) {
    float s = msum[r];
    for (int d = 1; d < 16; d <<= 1) s += __shfl_xor(s, d, 64);
    msum[r] = s;
  }
  if (l15 == 0) {
    long idx = ((long)(b * H_ + h)) * L_ + l0 + wave * 16 + l4 * 4;
    f32x4 o = {1.0f / msum[0], 1.0f / msum[1], 1.0f / msum[2], 1.0f / msum[3]};
    *(f32x4*)&sinv[idx] = o;
  }
}

// ---------------------------------------------------------------------------
// Attention pass B v2 (+ restored launch_bounds — r12's regression was the
// missing attribute capping VGPRs at 64 and spilling ~110 live regs to
// scratch: WRITE_SIZE 41->253MB).  128x128 tile, 512 threads.  Q global->reg
// prefetched one h ahead via explicit double register sets; K in 32KB LDS
// dbuf; per-iter issues = Q(4)+K(2) -> vmcnt(6) retires prev iter's loads.
// ---------------------------------------------------------------------------
__global__ __launch_bounds__(512, 2) void attn_probs_kernel(
    const __bf16* __restrict__ qk, const float* __restrict__ sinv,
    const float* __restrict__ relTab, __bf16* __restrict__ P,
    float* __restrict__ rowsumT) {
  __shared__ __bf16 sKl[2][128 * 64];
  const int tid = threadIdx.x, wave = tid >> 6, lane = tid & 63;
  const int l15 = lane & 15, l4 = lane >> 4;
  const int m0 = blockIdx.x * 128, l0 = blockIdx.y * 128, b = blockIdx.z;
  const int wr2 = wave & 3, wc2 = wave >> 2;
  const __bf16* Kb = qk + ((long)(b * L_ + m0)) * QKS + 1024;

  const int rowbase = l0 + wr2 * 32 + l4 * 4;
  // per-lane Q fragment base pointers (row-halves 0/+16 of this wave's 32)
  const __bf16* qp0 =
      qk + ((long)(b * L_ + l0 + wr2 * 32 + l15)) * QKS + l4 * 8;
  const __bf16* qp1 = qp0 + 16 * QKS;

  float wacc[4][8];  // [ni][fi*4+r]
#pragma unroll
  for (int i = 0; i < 4; ++i)
#pragma unroll
    for (int j = 0; j < 8; ++j) wacc[i][j] = 0.f;

  bf16x8 qA[2][2], qB[2][2];
  // prologue: Q[0] (4 loads) + stage K[0] (2 loads) -> 6 outstanding
  qA[0][0] = *(const bf16x8*)(qp0);
  qA[0][1] = *(const bf16x8*)(qp0 + 32);
  qA[1][0] = *(const bf16x8*)(qp1);
  qA[1][1] = *(const bf16x8*)(qp1 + 32);
  stage_tile128_512(sKl[0], Kb, QKS, tid);

  auto BODY = [&](bf16x8(&qc)[2][2], bf16x8(&qn)[2][2], int h, int p) {
    const int hn = (h + 1 < H_) ? h + 1 : H_ - 1;
    // prefetch Q[h+1] into the OTHER register set + stage K[h+1]
    qn[0][0] = *(const bf16x8*)(qp0 + hn * 64);
    qn[0][1] = *(const bf16x8*)(qp0 + hn * 64 + 32);
    qn[1][0] = *(const bf16x8*)(qp1 + hn * 64);
    qn[1][1] = *(const bf16x8*)(qp1 + hn * 64 + 32);
    stage_tile128_512(sKl[p ^ 1], Kb + hn * 64, QKS, tid);
    // retire everything older than this iter's 6 issues: prev {Q,K,iv}
    asm volatile("s_waitcnt vmcnt(6)" ::: "memory");
    __builtin_amdgcn_s_barrier();
    const float* svh = &sinv[((long)(b * H_ + h)) * L_];
    f32x4 iv0 = *(const f32x4*)&svh[rowbase];
    f32x4 iv1 = *(const f32x4*)&svh[rowbase + 16];
#pragma unroll
    for (int ni = 0; ni < 4; ++ni) {
      const int rB = wc2 * 64 + ni * 16 + l15;
      bf16x8 b0 = RD_FRAG(sKl[p], rB, 0);
      bf16x8 b1 = RD_FRAG(sKl[p], rB, 1);
#pragma unroll
      for (int fi = 0; fi < 2; ++fi) {
        f32x4 s = (f32x4){0.f, 0.f, 0.f, 0.f};
        s = __builtin_amdgcn_mfma_f32_16x16x32_bf16(qc[fi][0], b0, s, 0, 0, 0);
        s = __builtin_amdgcn_mfma_f32_16x16x32_bf16(qc[fi][1], b1, s, 0, 0, 0);
#pragma unroll
        for (int r = 0; r < 4; ++r)
          wacc[ni][fi * 4 + r] += fexp2(s[r]) * (fi ? iv1[r] : iv0[r]);
      }
    }
    asm volatile("" ::: "memory");
    __builtin_amdgcn_s_barrier();  // all reads of sKl[p] done
  };

  for (int hh = 0; hh < H_; hh += 2) {
    BODY(qA, qB, hh, 0);
    BODY(qB, qA, hh + 1, 1);
  }

  float rowpart[2][4] = {{0.f, 0.f, 0.f, 0.f}, {0.f, 0.f, 0.f, 0.f}};
#pragma unroll
  for (int ni = 0; ni < 4; ++ni) {
#pragma unroll
    for (int fi = 0; fi < 2; ++fi) {
#pragma unroll
      for (int r = 0; r < 4; ++r) {
        int row = rowbase + fi * 16 + r;
        int col = m0 + wc2 * 64 + ni * 16 + l15;
        float relL = relTab[row - col + 2048];  // already * log2e
        float pv = fexp2(fmaf(wacc[ni][fi * 4 + r], LOG2E_H, relL));
        P[((long)b * L_ + row) * L_ + col] = (__bf16)pv;
        rowpart[fi][r] += pv;
      }
    }
  }
#pragma unroll
  for (int fi = 0; fi < 2; ++fi) {
#pragma unroll
    for (int r = 0; r < 4; ++r) {
      float s = rowpart[fi][r];
      s += __shfl_xor(s, 1, 16);
      s += __shfl_xor(s, 2, 16);
      s += __shfl_xor(s, 4, 16);
      s += __shfl_xor(s, 8, 16);
      if (l15 == 0) {
        int row = rowbase + fi * 16 + r;
        rowsumT[((long)b * L_ + row) * 32 + (m0 >> 6) + wc2] = s;
      }
    }
  }
}

// ---------------------------------------------------------------------------
__device__ __forceinline__ void wave_reduce2(float& a, float& b) {
#pragma unroll
  for (int d = 1; d < 64; d <<= 1) {
    a += __shfl_xor(a, d, 64);
    b += __shfl_xor(b, d, 64);
  }
}

// h1 = LN(h + rinv*(p0+p1)); h2 = LN(h1).  h2 written in bf16 only.
__global__ __launch_bounds__(256, 4) void ln12_kernel(
    const float* __restrict__ hin, const __bf16* __restrict__ p0,
    const __bf16* __restrict__ p1, const float* __restrict__ rowsumT,
    const float* __restrict__ w1, const float* __restrict__ b1,
    const float* __restrict__ w2, const float* __restrict__ b2,
    __bf16* __restrict__ h2b) {
  __shared__ float sh[9];
  const int tid = threadIdx.x;
  const long row = blockIdx.x;
  const long base = row * E_ + tid * 4;
  if (tid < 32) {
    float s = rowsumT[row * 32 + tid];
#pragma unroll
    for (int d = 1; d < 32; d <<= 1) s += __shfl_xor(s, d, 32);
    if (tid == 0) sh[8] = s;
  }
  f32x4 hv = *(const f32x4*)&hin[base];
  bf16x4 p0v = *(const bf16x4*)&p0[base];
  bf16x4 p1v = *(const bf16x4*)&p1[base];
  __syncthreads();
  const float rinv = 1.0f / sh[8];
  float y[4];
  float s1 = 0.f, s2 = 0.f;
#pragma unroll
  for (int j = 0; j < 4; ++j) {
    y[j] = hv[j] + rinv * ((float)p0v[j] + (float)p1v[j]);
    s1 += y[j];
    s2 += y[j] * y[j];
  }
  wave_reduce2(s1, s2);
  if ((tid & 63) == 0) { sh[(tid >> 6) * 2] = s1; sh[(tid >> 6) * 2 + 1] = s2; }
  __syncthreads();
  s1 = sh[0] + sh[2] + sh[4] + sh[6];
  s2 = sh[1] + sh[3] + sh[5] + sh[7];
  float mean = s1 * (1.f / E_);
  float var = s2 * (1.f / E_) - mean * mean;
  float rs = rsqrtf(var + EPS_);
  f32x4 wv = *(const f32x4*)&w1[tid * 4];
  f32x4 bv = *(const f32x4*)&b1[tid * 4];
  float h1[4];
  s1 = 0.f; s2 = 0.f;
#pragma unroll
  for (int j = 0; j < 4; ++j) {
    h1[j] = (y[j] - mean) * rs * wv[j] + bv[j];
    s1 += h1[j];
    s2 += h1[j] * h1[j];
  }
  __syncthreads();
  wave_reduce2(s1, s2);
  if ((tid & 63) == 0) { sh[(tid >> 6) * 2] = s1; sh[(tid >> 6) * 2 + 1] = s2; }
  __syncthreads();
  s1 = sh[0] + sh[2] + sh[4] + sh[6];
  s2 = sh[1] + sh[3] + sh[5] + sh[7];
  mean = s1 * (1.f / E_);
  var = s2 * (1.f / E_) - mean * mean;
  rs = rsqrtf(var + EPS_);
  wv = *(const f32x4*)&w2[tid * 4];
  bv = *(const f32x4*)&b2[tid * 4];
  bf16x4 ob;
#pragma unroll
  for (int j = 0; j < 4; ++j)
    ob[j] = (__bf16)((h1[j] - mean) * rs * wv[j] + bv[j]);
  *(bf16x4*)&h2b[base] = ob;
}

// out = LN(h2 + (p0+p1+b2)).  h2 read as bf16; outb overwrites after read.
__global__ __launch_bounds__(256, 4) void ln3_kernel(
    const __bf16* __restrict__ h2b_in, const __bf16* __restrict__ p0,
    const __bf16* __restrict__ p1, const float* __restrict__ bias2,
    const float* __restrict__ w3, const float* __restrict__ b3,
    float* __restrict__ outf, __bf16* __restrict__ outb) {
  __shared__ float sh[8];
  const int tid = threadIdx.x;
  const long row = blockIdx.x;
  const long base = row * E_ + tid * 4;
  bf16x4 hv = *(const bf16x4*)&h2b_in[base];
  bf16x4 p0v = *(const bf16x4*)&p0[base];
  bf16x4 p1v = *(const bf16x4*)&p1[base];
  f32x4 b2v = *(const f32x4*)&bias2[tid * 4];
  float y[4];
  float s1 = 0.f, s2 = 0.f;
#pragma unroll
  for (int j = 0; j < 4; ++j) {
    y[j] = (float)hv[j] + (float)p0v[j] + (float)p1v[j] + b2v[j];
    s1 += y[j];
    s2 += y[j] * y[j];
  }
  wave_reduce2(s1, s2);
  if ((tid & 63) == 0) { sh[(tid >> 6) * 2] = s1; sh[(tid >> 6) * 2 + 1] = s2; }
  __syncthreads();
  s1 = sh[0] + sh[2] + sh[4] + sh[6];
  s2 = sh[1] + sh[3] + sh[5] + sh[7];
  float mean = s1 * (1.f / E_);
  float var = s2 * (1.f / E_) - mean * mean;
  float rs = rsqrtf(var + EPS_);
  f32x4 wv = *(const f32x4*)&w3[tid * 4];
  f32x4 bv = *(const f32x4*)&b3[tid * 4];
  f32x4 o;
  bf16x4 ob;
#pragma unroll
  for (int j = 0; j < 4; ++j) {
    float v = (y[j] - mean) * rs * wv[j] + bv[j];
    o[j] = v;
    ob[j] = (__bf16)v;
  }
  *(f32x4*)&outf[base] = o;
  *(bf16x4*)&outb[base] = ob;
}

// ---------------------------------------------------------------------------
__global__ __launch_bounds__(256, 4) void transpose_kernel(
    const __bf16* __restrict__ X, __bf16* __restrict__ XT) {
  __shared__ __bf16 t[64 * 66];
  const int l0 = blockIdx.x * 64, e0 = blockIdx.y * 64, b = blockIdx.z;
  const int tid = threadIdx.x;
#pragma unroll
  for (int r = 0; r < 2; ++r) {
    int c = tid + 256 * r;
    int rw = c >> 3, c8 = (c & 7) * 8;
    *(bf16x8*)&t[rw * 66 + c8] =
        *(const bf16x8*)&X[((long)(b * L_) + l0 + rw) * E_ + e0 + c8];
  }
  __syncthreads();
#pragma unroll
  for (int r = 0; r < 2; ++r) {
    int c = tid + 256 * r;
    int er = c >> 3, l8 = (c & 7) * 8;
    bf16x8 v;
#pragma unroll
    for (int j = 0; j < 8; ++j) v[j] = t[(l8 + j) * 66 + er];
    *(bf16x8*)&XT[((long)(b * E_) + e0 + er) * L_ + l0 + l8] = v;
  }
}

__global__ __launch_bounds__(256, 4) void f32_to_bf16_kernel(
    const float* __restrict__ x, __bf16* __restrict__ y) {
  long i = ((long)blockIdx.x * 256 + threadIdx.x) * 4;
  f32x4 v = *(const f32x4*)&x[i];
  bf16x4 o;
#pragma unroll
  for (int j = 0; j < 4; ++j) o[j] = (__bf16)v[j];
  *(bf16x4*)&y[i] = o;
}

// fused [D][2048][1024] Wqk (rows 0-1023 = Wq * EXPSC, 1024-2047 = Wk), bf16
__global__ __launch_bounds__(256, 4) void build_wqk_kernel(
    const float* __restrict__ Wq, const float* __restrict__ Wk,
    __bf16* __restrict__ out) {
  long i = ((long)blockIdx.x * 256 + threadIdx.x) * 4;
  long d = i >> 21;
  long rem = i & ((1L << 21) - 1);
  long row = rem >> 10, col = rem & 1023;
  const bool isQ = (row < 1024);
  const float* src = isQ ? &Wq[(d << 20) + (row << 10) + col]
                         : &Wk[(d << 20) + ((row - 1024) << 10) + col];
  const float sc = isQ ? EXPSC : 1.0f;
  f32x4 v = *(const f32x4*)src;
  bf16x4 o;
#pragma unroll
  for (int j = 0; j < 4; ++j) o[j] = (__bf16)(v[j] * sc);
  *(bf16x4*)&out[i] = o;
}

__global__ __launch_bounds__(256, 4) void build_bqk_kernel(
    const float* __restrict__ bq, const float* __restrict__ bk,
    float* __restrict__ out) {
  int i = blockIdx.x * 256 + threadIdx.x;  // D*2048
  int d = i >> 11, c = i & 2047;
  out[i] = (c < 1024) ? bq[d * 1024 + c] * EXPSC : bk[d * 1024 + c - 1024];
}

// relTab[d+2048] = exp(-|d|/16) * log2(e)
__global__ __launch_bounds__(256, 4) void build_rel_kernel(
    float* __restrict__ relTab) {
  int i = blockIdx.x * 256 + threadIdx.x;  // 4096
  relTab[i] = __expf(-fabsf((float)(i - 2048)) * (1.0f / 16.0f)) * LOG2E;
}

// ---------------------------------------------------------------------------
extern "C" void kernel_launch(void* const* d_in, const int* in_sizes, int n_in,
                              void* d_out, int out_size, void* d_ws,
                              size_t ws_size, hipStream_t stream) {
  const float* x = (const float*)d_in[0];
  const float* Wq = (const float*)d_in[1];
  const float* Wk = (const float*)d_in[2];
  const float* bq = (const float*)d_in[3];
  const float* bk = (const float*)d_in[4];
  const float* l1w = (const float*)d_in[5];
  const float* l1b = (const float*)d_in[6];
  const float* l2w = (const float*)d_in[7];
  const float* l2b = (const float*)d_in[8];
  const float* l3w = (const float*)d_in[9];
  const float* l3b = (const float*)d_in[10];
  const float* W1 = (const float*)d_in[11];
  const float* b1 = (const float*)d_in[12];
  const float* W2 = (const float*)d_in[13];
  const float* b2 = (const float*)d_in[14];

  char* p = (char*)d_ws;
  auto take = [&](size_t bytes) -> char* {
    char* r = p;
    p += (bytes + 255) & ~(size_t)255;
    return r;
  };
  __bf16* wqk_bf = (__bf16*)take((size_t)D_ * 2048 * 1024 * 2);
  __bf16* w1_bf = (__bf16*)take((size_t)D_ * F_ * E_ * 2);
  __bf16* w2_bf = (__bf16*)take((size_t)D_ * E_ * F_ * 2);
  __bf16* h_bf = (__bf16*)take((size_t)BL_ * E_ * 2);
  __bf16* hT = (__bf16*)take((size_t)BL_ * E_ * 2);
  __bf16* qk_bf = (__bf16*)take((size_t)BL_ * QKS * 2);     // union with ffmid
  __bf16* Pbuf = (__bf16*)take((size_t)B_ * L_ * L_ * 2);   // union with ffmid
  __bf16* ffmid = qk_bf;  // [BL][F] bf16 == qk+P exactly
  float* bqk = (float*)take((size_t)D_ * 2048 * 4);
  float* relTab = (float*)take((size_t)4096 * 4);
  float* sinv = (float*)take((size_t)B_ * H_ * L_ * 4);
  float* rowsumT = (float*)take((size_t)BL_ * 32 * 4);
  __bf16* partB = (__bf16*)take((size_t)2 * BL_ * E_ * 2);  // bf16 partials
  __bf16* part0 = partB;
  __bf16* part1 = partB + (size_t)BL_ * E_;
  float* hbuf = (float*)take((size_t)BL_ * E_ * 4);

  // --- setup ---
  build_wqk_kernel<<<D_ * 2048 * 1024 / 1024, 256, 0, stream>>>(Wq, Wk, wqk_bf);
  build_bqk_kernel<<<D_ * 2048 / 256, 256, 0, stream>>>(bq, bk, bqk);
  build_rel_kernel<<<16, 256, 0, stream>>>(relTab);
  f32_to_bf16_kernel<<<D_ * F_ * E_ / 1024, 256, 0, stream>>>(W1, w1_bf);
  f32_to_bf16_kernel<<<D_ * E_ * F_ / 1024, 256, 0, stream>>>(W2, w2_bf);
  f32_to_bf16_kernel<<<BL_ * E_ / 1024, 256, 0, stream>>>(x, h_bf);
  transpose_kernel<<<dim3(L_ / 64, E_ / 64, B_), 256, 0, stream>>>(h_bf, hT);

  const float* h_in = x;
  for (int d = 0; d < D_; ++d) {
    // fused QK projection: [BL][2048] = h @ [Wq*c;Wk]^T + [bq*c;bk]  (256 wgs)
    gemm8p<1><<<dim3(256, 1), 512, 0, stream>>>(
        h_bf, wqk_bf + (size_t)d * 2048 * 1024, qk_bf, bqk + d * 2048, BL_,
        2048, E_, E_, E_, 1, 0, 0, 0, 0);
    attn_stats_kernel<<<dim3(L_ / 128, H_, B_), 512, 0, stream>>>(qk_bf, sinv);
    attn_probs_kernel<<<dim3(L_ / 128, L_ / 128, B_), 512, 0, stream>>>(
        qk_bf, sinv, relTab, Pbuf, rowsumT);
    // sa-partials = P @ h  (4 batches x split-K2 = 8 z -> 256 wgs, bf16 out)
    gemm8p<0><<<dim3(32, 8), 512, 0, stream>>>(
        Pbuf, hT, partB, nullptr, L_, E_, L_ / 2, L_, L_, 2, (long)L_ * L_,
        (long)E_ * L_, (long)L_ * E_, (long)BL_ * E_);
    // h2 (bf16) -> h_bf
    ln12_kernel<<<BL_, 256, 0, stream>>>(h_in, part0, part1, rowsumT,
                                         l1w + d * E_, l1b + d * E_,
                                         l2w + d * E_, l2b + d * E_, h_bf);
    // FFN1 (512 wgs)
    gemm8p<2><<<dim3(512, 1), 512, 0, stream>>>(
        h_bf, w1_bf + (size_t)d * F_ * E_, ffmid, b1 + d * F_, BL_, F_, E_,
        E_, E_, 1, 0, 0, 0, 0);
    // FFN2 partials (split-K2 -> 256 wgs, bf16 out)
    gemm8p<0><<<dim3(128, 2), 512, 0, stream>>>(
        ffmid, w2_bf + (size_t)d * E_ * F_, partB, nullptr, BL_, E_, F_ / 2,
        F_, F_, 2, 0, 0, 0, (long)BL_ * E_);
    float* outp = (d == D_ - 1) ? (float*)d_out : hbuf;
    ln3_kernel<<<BL_, 256, 0, stream>>>(h_bf, part0, part1, b2 + d * E_,
                                        l3w + d * E_, l3b + d * E_, outp,
                                        h_bf);
    if (d < D_ - 1) {
      transpose_kernel<<<dim3(L_ / 64, E_ / 64, B_), 256, 0, stream>>>(h_bf, hT);
      h_in = hbuf;
    }
  }
}

// Round 14
// 2170.795 us; speedup vs baseline: 1.3003x; 1.2039x over previous
//
#include <hip/hip_runtime.h>

#define D_ 6
#define B_ 4
#define L_ 2048
#define E_ 1024
#define H_ 16
#define F_ 4096
#define BL_ (B_ * L_)
#define QKS 2048
#define EPS_ 1e-5f
// Q pre-scale: exp(s*0.125) == exp2(s * 0.125*log2(e)); folded into Wq/bq.
#define EXPSC 0.18033688011112042f
#define LOG2E 1.4426950408889634f
#define LOG2E_H (LOG2E / 16.0f)

typedef __bf16 bf16x8 __attribute__((ext_vector_type(8)));
typedef __bf16 bf16x4 __attribute__((ext_vector_type(4)));
typedef float f32x4 __attribute__((ext_vector_type(4)));

__device__ __forceinline__ float fexp2(float x) {
  return __builtin_amdgcn_exp2f(x);  // raw v_exp_f32 (args in safe range)
}

__device__ __forceinline__ void gload_lds16(const void* g, void* l) {
  __builtin_amdgcn_global_load_lds(
      (const __attribute__((address_space(1))) void*)g,
      (__attribute__((address_space(3))) void*)l, 16, 0, 0);
}

// 64x64 tile with 512 threads: 1 load/thread.  Source pre-swizzled
// (cu ^= row&7) so swizzled ds_read_b128 is conflict-free.
__device__ __forceinline__ void stage_tile64_512(__bf16* ldsb,
                                                 const __bf16* gbase, long ldg,
                                                 int tid) {
  int row = tid >> 3, cu = tid & 7;
  const __bf16* src = gbase + (long)row * ldg + ((cu ^ (row & 7)) << 3);
  gload_lds16(src, ldsb + (long)((tid & ~63) << 3));
}

// 128x64 tile (16KB) with 512 threads: 2 loads/thread.
__device__ __forceinline__ void stage_tile128_512(__bf16* ldsb,
                                                  const __bf16* gbase,
                                                  long ldg, int tid) {
#pragma unroll
  for (int j = 0; j < 2; ++j) {
    int unit = j * 512 + tid;
    int row = unit >> 3, cu = unit & 7;
    const __bf16* src = gbase + (long)row * ldg + ((cu ^ (row & 7)) << 3);
    gload_lds16(src, ldsb + (long)((j * 512 + (tid & ~63)) << 3));
  }
}

// swizzled fragment read from a linear [R][64] tile: row r_, k-slice kk
#define RD_FRAG(ldsb, r_, kk) \
  (*(const bf16x8*)&(ldsb)[((r_) * 8 + (((kk) * 4 + l4) ^ ((r_) & 7))) * 8])

// ---------------------------------------------------------------------------
// 256x256 8-phase GEMM.  C = A * B^T.  (unchanged from rounds 8-13)
// EPI: 0 = raw bf16 (split-K partial); 1 = +bias bf16; 2 = +bias relu bf16.
// ---------------------------------------------------------------------------
#define LDA_SUB(P, MH)                                                        \
  _Pragma("unroll") for (int mi = 0; mi < 4; ++mi)                            \
  _Pragma("unroll") for (int kk = 0; kk < 2; ++kk) {                          \
    int r_ = wr + (MH) * 64 + mi * 16 + l15;                                  \
    int cu_ = kk * 4 + l4;                                                    \
    aF[mi][kk] = *(const bf16x8*)&lds[P][0][(r_ * 8 + (cu_ ^ (r_ & 7))) * 8]; \
  }

#define LDB_SUB(P, BF, NH)                                                    \
  _Pragma("unroll") for (int ni = 0; ni < 2; ++ni)                            \
  _Pragma("unroll") for (int kk = 0; kk < 2; ++kk) {                          \
    int r_ = wc + (NH) * 32 + ni * 16 + l15;                                  \
    int cu_ = kk * 4 + l4;                                                    \
    BF[ni][kk] = *(const bf16x8*)&lds[P][1][(r_ * 8 + (cu_ ^ (r_ & 7))) * 8]; \
  }

#define MFMA_Q(AF, BF, MH, NH)                                                \
  _Pragma("unroll") for (int mi = 0; mi < 4; ++mi)                            \
  _Pragma("unroll") for (int ni = 0; ni < 2; ++ni)                            \
  _Pragma("unroll") for (int kk = 0; kk < 2; ++kk)                            \
    acc[(MH) * 4 + mi][(NH) * 2 + ni] =                                       \
        __builtin_amdgcn_mfma_f32_16x16x32_bf16(                              \
            AF[mi][kk], BF[ni][kk], acc[(MH) * 4 + mi][(NH) * 2 + ni], 0, 0, 0);

#define PHASE_PRE()                                                           \
  __builtin_amdgcn_s_barrier();                                               \
  asm volatile("s_waitcnt lgkmcnt(0)" ::: "memory");                          \
  __builtin_amdgcn_sched_barrier(0);                                          \
  __builtin_amdgcn_s_setprio(1)

#define PHASE_POST()                                                          \
  __builtin_amdgcn_s_setprio(0);                                              \
  __builtin_amdgcn_sched_barrier(0);                                          \
  __builtin_amdgcn_s_barrier()

#define STAGE_A(BUFI, HF, K0)                                                 \
  do {                                                                        \
    gload_lds16(sA[HF][0] + (K0),                                             \
                &lds[BUFI][0][((HF) * 1024 + wave * 64) * 8]);                \
    gload_lds16(sA[HF][1] + (K0),                                             \
                &lds[BUFI][0][((HF) * 1024 + 512 + wave * 64) * 8]);          \
  } while (0)

#define STAGE_B(BUFI, HF, K0)                                                 \
  do {                                                                        \
    gload_lds16(sB[HF][0] + (K0),                                             \
                &lds[BUFI][1][((HF) * 1024 + wave * 64) * 8]);                \
    gload_lds16(sB[HF][1] + (K0),                                             \
                &lds[BUFI][1][((HF) * 1024 + 512 + wave * 64) * 8]);          \
  } while (0)

template <int EPI>
__global__ __launch_bounds__(512, 2) void gemm8p(
    const __bf16* __restrict__ A, const __bf16* __restrict__ Bm,
    __bf16* __restrict__ Cb, const float* __restrict__ bias, int M, int N,
    int K, int lda, int ldb, int zk, long strA, long strB, long strC,
    long strCk) {
  __shared__ __bf16 lds[2][2][256 * 64];
  const int tid = threadIdx.x;
  const int wave = tid >> 6, lane = tid & 63;
  const int l15 = lane & 15, l4 = lane >> 4;
  const int z = blockIdx.y;
  const int kc = (zk == 2) ? (z & 1) : 0;
  const int bat = (zk == 2) ? (z >> 1) : z;
  const __bf16* Ab = A + (long)bat * strA + (long)kc * K;
  const __bf16* Bb = Bm + (long)bat * strB + (long)kc * K;
  const long coff = (long)bat * strC + (long)kc * strCk;

  const int nbx = N >> 8;
  const int nwg = (M >> 8) * nbx;
  const int orig = blockIdx.x;
  const int qq = nwg >> 3, rr = nwg & 7;
  const int xcd = orig & 7, lid = orig >> 3;
  const int wg = (xcd < rr ? xcd * (qq + 1) : rr * (qq + 1) + (xcd - rr) * qq) + lid;
  const int row0 = (wg / nbx) * 256, col0 = (wg % nbx) * 256;
  const int wr = (wave >> 2) * 128;
  const int wc = (wave & 3) * 64;

  const int rsel = tid >> 3;
  const int swz = ((lane & 7) ^ (rsel & 7)) << 3;
  const __bf16* sA[2][2];
  const __bf16* sB[2][2];
#pragma unroll
  for (int hf = 0; hf < 2; ++hf)
#pragma unroll
    for (int j = 0; j < 2; ++j) {
      sA[hf][j] = Ab + (long)(row0 + hf * 128 + j * 64 + rsel) * lda + swz;
      sB[hf][j] = Bb + (long)(col0 + hf * 128 + j * 64 + rsel) * ldb + swz;
    }

  const int NT = K >> 6;
  STAGE_A(0, 0, 0);
  STAGE_A(0, 1, 0);
  STAGE_B(0, 0, 0);
  STAGE_B(0, 1, 0);
  STAGE_A(1, 0, 64);
  STAGE_B(1, 0, 64);
  STAGE_A(1, 1, 64);
  asm volatile("s_waitcnt vmcnt(6)" ::: "memory");
  __builtin_amdgcn_s_barrier();

  f32x4 acc[8][4];
#pragma unroll
  for (int i = 0; i < 8; ++i)
#pragma unroll
    for (int j = 0; j < 4; ++j) acc[i][j] = (f32x4){0.f, 0.f, 0.f, 0.f};
  bf16x8 aF[4][2], b0F[2][2], b1F[2][2];

  for (int t = 0; t < NT; ++t) {
    const int p = t & 1;
    const int kA = (t + 1 < NT ? t + 1 : NT - 1) << 6;
    const int kB = (t + 2 < NT ? t + 2 : NT - 1) << 6;
    LDA_SUB(p, 0);
    LDB_SUB(p, b0F, 0);
    STAGE_B(p ^ 1, 1, kA);
    PHASE_PRE();
    MFMA_Q(aF, b0F, 0, 0);
    PHASE_POST();
    LDB_SUB(p, b1F, 1);
    PHASE_PRE();
    MFMA_Q(aF, b1F, 0, 1);
    PHASE_POST();
    LDA_SUB(p, 1);
    STAGE_B(p, 0, kB);
    PHASE_PRE();
    MFMA_Q(aF, b0F, 1, 0);
    PHASE_POST();
    STAGE_A(p, 0, kB);
    STAGE_A(p, 1, kB);
    __builtin_amdgcn_s_barrier();
    __builtin_amdgcn_sched_barrier(0);
    __builtin_amdgcn_s_setprio(1);
    MFMA_Q(aF, b1F, 1, 1);
    __builtin_amdgcn_s_setprio(0);
    __builtin_amdgcn_sched_barrier(0);
    asm volatile("s_waitcnt vmcnt(6)" ::: "memory");
    __builtin_amdgcn_s_barrier();
  }
  asm volatile("s_waitcnt vmcnt(0)" ::: "memory");

#pragma unroll
  for (int i = 0; i < 8; ++i) {
    int row = row0 + wr + (i >> 2) * 64 + (i & 3) * 16 + l4 * 4;
#pragma unroll
    for (int j = 0; j < 4; ++j) {
      int col = col0 + wc + (j >> 1) * 32 + (j & 1) * 16 + l15;
      float bval = 0.f;
      if constexpr (EPI == 1 || EPI == 2) bval = bias[col];
#pragma unroll
      for (int r = 0; r < 4; ++r) {
        long crow = row + r;
        float v = acc[i][j][r];
        if constexpr (EPI == 1 || EPI == 2) v += bval;
        if constexpr (EPI == 2) v = fmaxf(v, 0.f);
        Cb[coff + crow * N + col] = (__bf16)v;
      }
    }
  }
}

// ---------------------------------------------------------------------------
// Attention pass A (widened): 256 Q-rows/block, 8 waves x 32 rows
// (2 row-groups of 16).  Q direct global->reg ONCE per block (scatter cost
// amortized over 32 K-tiles); K streamed as 64-row LDS tiles, vmcnt(1) dbuf.
// K traffic per (b,h) halves vs the 128-row version.
// ---------------------------------------------------------------------------
__global__ __launch_bounds__(512, 4) void attn_stats_kernel(
    const __bf16* __restrict__ qk, float* __restrict__ sinv) {
  __shared__ __bf16 sK[2][64 * 64];
  const int tid = threadIdx.x, wave = tid >> 6, lane = tid & 63;
  const int l15 = lane & 15, l4 = lane >> 4;
  const int l0 = blockIdx.x * 256, h = blockIdx.y, b = blockIdx.z;
  const __bf16* Kb = qk + ((long)b * L_) * QKS + 1024 + h * 64;

  // Q direct loads for both row-groups (drained by vmcnt(0) below)
  const __bf16* qp =
      qk + ((long)(b * L_ + l0 + wave * 32 + l15)) * QKS + h * 64 + l4 * 8;
  bf16x8 aF[2][2];
  aF[0][0] = *(const bf16x8*)qp;
  aF[0][1] = *(const bf16x8*)(qp + 32);
  aF[1][0] = *(const bf16x8*)(qp + 16 * QKS);
  aF[1][1] = *(const bf16x8*)(qp + 16 * QKS + 32);

  stage_tile64_512(sK[0], Kb, QKS, tid);
  asm volatile("s_waitcnt vmcnt(0)" ::: "memory");
  __builtin_amdgcn_s_barrier();

  float msum[2][4] = {{0.f, 0.f, 0.f, 0.f}, {0.f, 0.f, 0.f, 0.f}};
  int p = 0;
  for (int m0 = 0; m0 < 32; ++m0) {
    const int mn = (m0 + 1 < 32) ? m0 + 1 : 31;
    stage_tile64_512(sK[p ^ 1], Kb + (long)mn * 64 * QKS, QKS, tid);
    asm volatile("s_waitcnt vmcnt(1)" ::: "memory");  // buf[p] resident
    __builtin_amdgcn_s_barrier();
#pragma unroll
    for (int ni = 0; ni < 4; ++ni) {
      const int rB = ni * 16 + l15;
      bf16x8 b0 = RD_FRAG(sK[p], rB, 0);
      bf16x8 b1 = RD_FRAG(sK[p], rB, 1);
#pragma unroll
      for (int g = 0; g < 2; ++g) {
        f32x4 s = (f32x4){0.f, 0.f, 0.f, 0.f};
        s = __builtin_amdgcn_mfma_f32_16x16x32_bf16(aF[g][0], b0, s, 0, 0, 0);
        s = __builtin_amdgcn_mfma_f32_16x16x32_bf16(aF[g][1], b1, s, 0, 0, 0);
#pragma unroll
        for (int r = 0; r < 4; ++r) msum[g][r] += fexp2(s[r]);
      }
    }
    asm volatile("" ::: "memory");
    __builtin_amdgcn_s_barrier();
    p ^= 1;
  }
#pragma unroll
  for (int g = 0; g < 2; ++g) {
#pragma unroll
    for (int r = 0; r < 4; ++r) {
      float s = msum[g][r];
      for (int d = 1; d < 16; d <<= 1) s += __shfl_xor(s, d, 64);
      msum[g][r] = s;
    }
    if (l15 == 0) {
      long idx =
          ((long)(b * H_ + h)) * L_ + l0 + wave * 32 + g * 16 + l4 * 4;
      f32x4 o = {1.0f / msum[g][0], 1.0f / msum[g][1], 1.0f / msum[g][2],
                 1.0f / msum[g][3]};
      *(f32x4*)&sinv[idx] = o;
    }
  }
}

// ---------------------------------------------------------------------------
// Attention pass B (r9/r11 version — best measured, 72us): 128x128 output
// tile, 512 threads = 8 waves (4 row-groups x 2 col-halves).  Q+K 128-row
// LDS tiles double-buffered over h (coalesced gload_lds prefetch), vmcnt(4).
// Emits P row-sum partials -> rowsumT[row][32].
// ---------------------------------------------------------------------------
__global__ __launch_bounds__(512, 2) void attn_probs_kernel(
    const __bf16* __restrict__ qk, const float* __restrict__ sinv,
    const float* __restrict__ relTab, __bf16* __restrict__ P,
    float* __restrict__ rowsumT) {
  __shared__ __bf16 sQ[2][128 * 64];
  __shared__ __bf16 sKl[2][128 * 64];
  const int tid = threadIdx.x, wave = tid >> 6, lane = tid & 63;
  const int l15 = lane & 15, l4 = lane >> 4;
  const int m0 = blockIdx.x * 128, l0 = blockIdx.y * 128, b = blockIdx.z;
  const int wr2 = wave & 3, wc2 = wave >> 2;
  const __bf16* Qb = qk + ((long)(b * L_ + l0)) * QKS;
  const __bf16* Kb = qk + ((long)(b * L_ + m0)) * QKS + 1024;

  stage_tile128_512(sQ[0], Qb, QKS, tid);
  stage_tile128_512(sKl[0], Kb, QKS, tid);

  float wacc[4][8];  // [ni][fi*4+r]
#pragma unroll
  for (int i = 0; i < 4; ++i)
#pragma unroll
    for (int j = 0; j < 8; ++j) wacc[i][j] = 0.f;

  const int rA0 = wr2 * 32 + l15;
  const int rowbase = l0 + wr2 * 32 + l4 * 4;
  int p = 0;
  for (int h = 0; h < H_; ++h) {
    const int hn = (h + 1 < H_) ? h + 1 : H_ - 1;
    stage_tile128_512(sQ[p ^ 1], Qb + hn * 64, QKS, tid);
    stage_tile128_512(sKl[p ^ 1], Kb + hn * 64, QKS, tid);
    const float* svh = &sinv[((long)(b * H_ + h)) * L_];
    f32x4 iv0 = *(const f32x4*)&svh[rowbase];
    f32x4 iv1 = *(const f32x4*)&svh[rowbase + 16];
    asm volatile("s_waitcnt vmcnt(4)" ::: "memory");  // buf[p] resident
    __builtin_amdgcn_s_barrier();
    bf16x8 aF[2][2];
    aF[0][0] = RD_FRAG(sQ[p], rA0, 0);
    aF[0][1] = RD_FRAG(sQ[p], rA0, 1);
    aF[1][0] = RD_FRAG(sQ[p], rA0 + 16, 0);
    aF[1][1] = RD_FRAG(sQ[p], rA0 + 16, 1);
#pragma unroll
    for (int ni = 0; ni < 4; ++ni) {
      const int rB = wc2 * 64 + ni * 16 + l15;
      bf16x8 b0 = RD_FRAG(sKl[p], rB, 0);
      bf16x8 b1 = RD_FRAG(sKl[p], rB, 1);
#pragma unroll
      for (int fi = 0; fi < 2; ++fi) {
        f32x4 s = (f32x4){0.f, 0.f, 0.f, 0.f};
        s = __builtin_amdgcn_mfma_f32_16x16x32_bf16(aF[fi][0], b0, s, 0, 0, 0);
        s = __builtin_amdgcn_mfma_f32_16x16x32_bf16(aF[fi][1], b1, s, 0, 0, 0);
#pragma unroll
        for (int r = 0; r < 4; ++r)
          wacc[ni][fi * 4 + r] += fexp2(s[r]) * (fi ? iv1[r] : iv0[r]);
      }
    }
    asm volatile("" ::: "memory");
    __builtin_amdgcn_s_barrier();
    p ^= 1;
  }
  float rowpart[2][4] = {{0.f, 0.f, 0.f, 0.f}, {0.f, 0.f, 0.f, 0.f}};
#pragma unroll
  for (int ni = 0; ni < 4; ++ni) {
#pragma unroll
    for (int fi = 0; fi < 2; ++fi) {
#pragma unroll
      for (int r = 0; r < 4; ++r) {
        int row = rowbase + fi * 16 + r;
        int col = m0 + wc2 * 64 + ni * 16 + l15;
        float relL = relTab[row - col + 2048];  // already * log2e
        float pv = fexp2(fmaf(wacc[ni][fi * 4 + r], LOG2E_H, relL));
        P[((long)b * L_ + row) * L_ + col] = (__bf16)pv;
        rowpart[fi][r] += pv;
      }
    }
  }
#pragma unroll
  for (int fi = 0; fi < 2; ++fi) {
#pragma unroll
    for (int r = 0; r < 4; ++r) {
      float s = rowpart[fi][r];
      s += __shfl_xor(s, 1, 16);
      s += __shfl_xor(s, 2, 16);
      s += __shfl_xor(s, 4, 16);
      s += __shfl_xor(s, 8, 16);
      if (l15 == 0) {
        int row = rowbase + fi * 16 + r;
        rowsumT[((long)b * L_ + row) * 32 + (m0 >> 6) + wc2] = s;
      }
    }
  }
}

// ---------------------------------------------------------------------------
__device__ __forceinline__ void wave_reduce2(float& a, float& b) {
#pragma unroll
  for (int d = 1; d < 64; d <<= 1) {
    a += __shfl_xor(a, d, 64);
    b += __shfl_xor(b, d, 64);
  }
}

// h1 = LN(h + rinv*(p0+p1)); h2 = LN(h1).  h2 written in bf16 only.
__global__ __launch_bounds__(256, 4) void ln12_kernel(
    const float* __restrict__ hin, const __bf16* __restrict__ p0,
    const __bf16* __restrict__ p1, const float* __restrict__ rowsumT,
    const float* __restrict__ w1, const float* __restrict__ b1,
    const float* __restrict__ w2, const float* __restrict__ b2,
    __bf16* __restrict__ h2b) {
  __shared__ float sh[9];
  const int tid = threadIdx.x;
  const long row = blockIdx.x;
  const long base = row * E_ + tid * 4;
  if (tid < 32) {
    float s = rowsumT[row * 32 + tid];
#pragma unroll
    for (int d = 1; d < 32; d <<= 1) s += __shfl_xor(s, d, 32);
    if (tid == 0) sh[8] = s;
  }
  f32x4 hv = *(const f32x4*)&hin[base];
  bf16x4 p0v = *(const bf16x4*)&p0[base];
  bf16x4 p1v = *(const bf16x4*)&p1[base];
  __syncthreads();
  const float rinv = 1.0f / sh[8];
  float y[4];
  float s1 = 0.f, s2 = 0.f;
#pragma unroll
  for (int j = 0; j < 4; ++j) {
    y[j] = hv[j] + rinv * ((float)p0v[j] + (float)p1v[j]);
    s1 += y[j];
    s2 += y[j] * y[j];
  }
  wave_reduce2(s1, s2);
  if ((tid & 63) == 0) { sh[(tid >> 6) * 2] = s1; sh[(tid >> 6) * 2 + 1] = s2; }
  __syncthreads();
  s1 = sh[0] + sh[2] + sh[4] + sh[6];
  s2 = sh[1] + sh[3] + sh[5] + sh[7];
  float mean = s1 * (1.f / E_);
  float var = s2 * (1.f / E_) - mean * mean;
  float rs = rsqrtf(var + EPS_);
  f32x4 wv = *(const f32x4*)&w1[tid * 4];
  f32x4 bv = *(const f32x4*)&b1[tid * 4];
  float h1[4];
  s1 = 0.f; s2 = 0.f;
#pragma unroll
  for (int j = 0; j < 4; ++j) {
    h1[j] = (y[j] - mean) * rs * wv[j] + bv[j];
    s1 += h1[j];
    s2 += h1[j] * h1[j];
  }
  __syncthreads();
  wave_reduce2(s1, s2);
  if ((tid & 63) == 0) { sh[(tid >> 6) * 2] = s1; sh[(tid >> 6) * 2 + 1] = s2; }
  __syncthreads();
  s1 = sh[0] + sh[2] + sh[4] + sh[6];
  s2 = sh[1] + sh[3] + sh[5] + sh[7];
  mean = s1 * (1.f / E_);
  var = s2 * (1.f / E_) - mean * mean;
  rs = rsqrtf(var + EPS_);
  wv = *(const f32x4*)&w2[tid * 4];
  bv = *(const f32x4*)&b2[tid * 4];
  bf16x4 ob;
#pragma unroll
  for (int j = 0; j < 4; ++j)
    ob[j] = (__bf16)((h1[j] - mean) * rs * wv[j] + bv[j]);
  *(bf16x4*)&h2b[base] = ob;
}

// out = LN(h2 + (p0+p1+b2)).  h2 read as bf16; outb overwrites after read.
__global__ __launch_bounds__(256, 4) void ln3_kernel(
    const __bf16* __restrict__ h2b_in, const __bf16* __restrict__ p0,
    const __bf16* __restrict__ p1, const float* __restrict__ bias2,
    const float* __restrict__ w3, const float* __restrict__ b3,
    float* __restrict__ outf, __bf16* __restrict__ outb) {
  __shared__ float sh[8];
  const int tid = threadIdx.x;
  const long row = blockIdx.x;
  const long base = row * E_ + tid * 4;
  bf16x4 hv = *(const bf16x4*)&h2b_in[base];
  bf16x4 p0v = *(const bf16x4*)&p0[base];
  bf16x4 p1v = *(const bf16x4*)&p1[base];
  f32x4 b2v = *(const f32x4*)&bias2[tid * 4];
  float y[4];
  float s1 = 0.f, s2 = 0.f;
#pragma unroll
  for (int j = 0; j < 4; ++j) {
    y[j] = (float)hv[j] + (float)p0v[j] + (float)p1v[j] + b2v[j];
    s1 += y[j];
    s2 += y[j] * y[j];
  }
  wave_reduce2(s1, s2);
  if ((tid & 63) == 0) { sh[(tid >> 6) * 2] = s1; sh[(tid >> 6) * 2 + 1] = s2; }
  __syncthreads();
  s1 = sh[0] + sh[2] + sh[4] + sh[6];
  s2 = sh[1] + sh[3] + sh[5] + sh[7];
  float mean = s1 * (1.f / E_);
  float var = s2 * (1.f / E_) - mean * mean;
  float rs = rsqrtf(var + EPS_);
  f32x4 wv = *(const f32x4*)&w3[tid * 4];
  f32x4 bv = *(const f32x4*)&b3[tid * 4];
  f32x4 o;
  bf16x4 ob;
#pragma unroll
  for (int j = 0; j < 4; ++j) {
    float v = (y[j] - mean) * rs * wv[j] + bv[j];
    o[j] = v;
    ob[j] = (__bf16)v;
  }
  *(f32x4*)&outf[base] = o;
  *(bf16x4*)&outb[base] = ob;
}

// ---------------------------------------------------------------------------
__global__ __launch_bounds__(256, 4) void transpose_kernel(
    const __bf16* __restrict__ X, __bf16* __restrict__ XT) {
  __shared__ __bf16 t[64 * 66];
  const int l0 = blockIdx.x * 64, e0 = blockIdx.y * 64, b = blockIdx.z;
  const int tid = threadIdx.x;
#pragma unroll
  for (int r = 0; r < 2; ++r) {
    int c = tid + 256 * r;
    int rw = c >> 3, c8 = (c & 7) * 8;
    *(bf16x8*)&t[rw * 66 + c8] =
        *(const bf16x8*)&X[((long)(b * L_) + l0 + rw) * E_ + e0 + c8];
  }
  __syncthreads();
#pragma unroll
  for (int r = 0; r < 2; ++r) {
    int c = tid + 256 * r;
    int er = c >> 3, l8 = (c & 7) * 8;
    bf16x8 v;
#pragma unroll
    for (int j = 0; j < 8; ++j) v[j] = t[(l8 + j) * 66 + er];
    *(bf16x8*)&XT[((long)(b * E_) + e0 + er) * L_ + l0 + l8] = v;
  }
}

__global__ __launch_bounds__(256, 4) void f32_to_bf16_kernel(
    const float* __restrict__ x, __bf16* __restrict__ y) {
  long i = ((long)blockIdx.x * 256 + threadIdx.x) * 4;
  f32x4 v = *(const f32x4*)&x[i];
  bf16x4 o;
#pragma unroll
  for (int j = 0; j < 4; ++j) o[j] = (__bf16)v[j];
  *(bf16x4*)&y[i] = o;
}

// fused [D][2048][1024] Wqk (rows 0-1023 = Wq * EXPSC, 1024-2047 = Wk), bf16
__global__ __launch_bounds__(256, 4) void build_wqk_kernel(
    const float* __restrict__ Wq, const float* __restrict__ Wk,
    __bf16* __restrict__ out) {
  long i = ((long)blockIdx.x * 256 + threadIdx.x) * 4;
  long d = i >> 21;
  long rem = i & ((1L << 21) - 1);
  long row = rem >> 10, col = rem & 1023;
  const bool isQ = (row < 1024);
  const float* src = isQ ? &Wq[(d << 20) + (row << 10) + col]
                         : &Wk[(d << 20) + ((row - 1024) << 10) + col];
  const float sc = isQ ? EXPSC : 1.0f;
  f32x4 v = *(const f32x4*)src;
  bf16x4 o;
#pragma unroll
  for (int j = 0; j < 4; ++j) o[j] = (__bf16)(v[j] * sc);
  *(bf16x4*)&out[i] = o;
}

__global__ __launch_bounds__(256, 4) void build_bqk_kernel(
    const float* __restrict__ bq, const float* __restrict__ bk,
    float* __restrict__ out) {
  int i = blockIdx.x * 256 + threadIdx.x;  // D*2048
  int d = i >> 11, c = i & 2047;
  out[i] = (c < 1024) ? bq[d * 1024 + c] * EXPSC : bk[d * 1024 + c - 1024];
}

// relTab[d+2048] = exp(-|d|/16) * log2(e)
__global__ __launch_bounds__(256, 4) void build_rel_kernel(
    float* __restrict__ relTab) {
  int i = blockIdx.x * 256 + threadIdx.x;  // 4096
  relTab[i] = __expf(-fabsf((float)(i - 2048)) * (1.0f / 16.0f)) * LOG2E;
}

// ---------------------------------------------------------------------------
extern "C" void kernel_launch(void* const* d_in, const int* in_sizes, int n_in,
                              void* d_out, int out_size, void* d_ws,
                              size_t ws_size, hipStream_t stream) {
  const float* x = (const float*)d_in[0];
  const float* Wq = (const float*)d_in[1];
  const float* Wk = (const float*)d_in[2];
  const float* bq = (const float*)d_in[3];
  const float* bk = (const float*)d_in[4];
  const float* l1w = (const float*)d_in[5];
  const float* l1b = (const float*)d_in[6];
  const float* l2w = (const float*)d_in[7];
  const float* l2b = (const float*)d_in[8];
  const float* l3w = (const float*)d_in[9];
  const float* l3b = (const float*)d_in[10];
  const float* W1 = (const float*)d_in[11];
  const float* b1 = (const float*)d_in[12];
  const float* W2 = (const float*)d_in[13];
  const float* b2 = (const float*)d_in[14];

  char* p = (char*)d_ws;
  auto take = [&](size_t bytes) -> char* {
    char* r = p;
    p += (bytes + 255) & ~(size_t)255;
    return r;
  };
  __bf16* wqk_bf = (__bf16*)take((size_t)D_ * 2048 * 1024 * 2);
  __bf16* w1_bf = (__bf16*)take((size_t)D_ * F_ * E_ * 2);
  __bf16* w2_bf = (__bf16*)take((size_t)D_ * E_ * F_ * 2);
  __bf16* h_bf = (__bf16*)take((size_t)BL_ * E_ * 2);
  __bf16* hT = (__bf16*)take((size_t)BL_ * E_ * 2);
  __bf16* qk_bf = (__bf16*)take((size_t)BL_ * QKS * 2);     // union with ffmid
  __bf16* Pbuf = (__bf16*)take((size_t)B_ * L_ * L_ * 2);   // union with ffmid
  __bf16* ffmid = qk_bf;  // [BL][F] bf16 == qk+P exactly
  float* bqk = (float*)take((size_t)D_ * 2048 * 4);
  float* relTab = (float*)take((size_t)4096 * 4);
  float* sinv = (float*)take((size_t)B_ * H_ * L_ * 4);
  float* rowsumT = (float*)take((size_t)BL_ * 32 * 4);
  __bf16* partB = (__bf16*)take((size_t)2 * BL_ * E_ * 2);  // bf16 partials
  __bf16* part0 = partB;
  __bf16* part1 = partB + (size_t)BL_ * E_;
  float* hbuf = (float*)take((size_t)BL_ * E_ * 4);

  // --- setup ---
  build_wqk_kernel<<<D_ * 2048 * 1024 / 1024, 256, 0, stream>>>(Wq, Wk, wqk_bf);
  build_bqk_kernel<<<D_ * 2048 / 256, 256, 0, stream>>>(bq, bk, bqk);
  build_rel_kernel<<<16, 256, 0, stream>>>(relTab);
  f32_to_bf16_kernel<<<D_ * F_ * E_ / 1024, 256, 0, stream>>>(W1, w1_bf);
  f32_to_bf16_kernel<<<D_ * E_ * F_ / 1024, 256, 0, stream>>>(W2, w2_bf);
  f32_to_bf16_kernel<<<BL_ * E_ / 1024, 256, 0, stream>>>(x, h_bf);
  transpose_kernel<<<dim3(L_ / 64, E_ / 64, B_), 256, 0, stream>>>(h_bf, hT);

  const float* h_in = x;
  for (int d = 0; d < D_; ++d) {
    // fused QK projection: [BL][2048] = h @ [Wq*c;Wk]^T + [bq*c;bk]  (256 wgs)
    gemm8p<1><<<dim3(256, 1), 512, 0, stream>>>(
        h_bf, wqk_bf + (size_t)d * 2048 * 1024, qk_bf, bqk + d * 2048, BL_,
        2048, E_, E_, E_, 1, 0, 0, 0, 0);
    attn_stats_kernel<<<dim3(L_ / 256, H_, B_), 512, 0, stream>>>(qk_bf, sinv);
    attn_probs_kernel<<<dim3(L_ / 128, L_ / 128, B_), 512, 0, stream>>>(
        qk_bf, sinv, relTab, Pbuf, rowsumT);
    // sa-partials = P @ h  (4 batches x split-K2 = 8 z -> 256 wgs, bf16 out)
    gemm8p<0><<<dim3(32, 8), 512, 0, stream>>>(
        Pbuf, hT, partB, nullptr, L_, E_, L_ / 2, L_, L_, 2, (long)L_ * L_,
        (long)E_ * L_, (long)L_ * E_, (long)BL_ * E_);
    // h2 (bf16) -> h_bf
    ln12_kernel<<<BL_, 256, 0, stream>>>(h_in, part0, part1, rowsumT,
                                         l1w + d * E_, l1b + d * E_,
                                         l2w + d * E_, l2b + d * E_, h_bf);
    // FFN1 (512 wgs)
    gemm8p<2><<<dim3(512, 1), 512, 0, stream>>>(
        h_bf, w1_bf + (size_t)d * F_ * E_, ffmid, b1 + d * F_, BL_, F_, E_,
        E_, E_, 1, 0, 0, 0, 0);
    // FFN2 partials (split-K2 -> 256 wgs, bf16 out)
    gemm8p<0><<<dim3(128, 2), 512, 0, stream>>>(
        ffmid, w2_bf + (size_t)d * E_ * F_, partB, nullptr, BL_, E_, F_ / 2,
        F_, F_, 2, 0, 0, 0, (long)BL_ * E_);
    float* outp = (d == D_ - 1) ? (float*)d_out : hbuf;
    ln3_kernel<<<BL_, 256, 0, stream>>>(h_bf, part0, part1, b2 + d * E_,
                                        l3w + d * E_, l3b + d * E_, outp,
                                        h_bf);
    if (d < D_ - 1) {
      transpose_kernel<<<dim3(L_ / 64, E_ / 64, B_), 256, 0, stream>>>(h_bf, hT);
      h_in = hbuf;
    }
  }
}

// Round 15
// 2152.743 us; speedup vs baseline: 1.3112x; 1.0084x over previous
//
#include <hip/hip_runtime.h>

#define D_ 6
#define B_ 4
#define L_ 2048
#define E_ 1024
#define H_ 16
#define F_ 4096
#define BL_ (B_ * L_)
#define QKS 2048
#define EPS_ 1e-5f
// Q pre-scale: exp(s*0.125) == exp2(s * 0.125*log2(e)); folded into Wq/bq.
#define EXPSC 0.18033688011112042f
#define LOG2E 1.4426950408889634f
#define LOG2E_H (LOG2E / 16.0f)

typedef __bf16 bf16x8 __attribute__((ext_vector_type(8)));
typedef __bf16 bf16x4 __attribute__((ext_vector_type(4)));
typedef float f32x4 __attribute__((ext_vector_type(4)));

__device__ __forceinline__ float fexp2(float x) {
  return __builtin_amdgcn_exp2f(x);  // raw v_exp_f32 (args in safe range)
}

__device__ __forceinline__ void gload_lds16(const void* g, void* l) {
  __builtin_amdgcn_global_load_lds(
      (const __attribute__((address_space(1))) void*)g,
      (__attribute__((address_space(3))) void*)l, 16, 0, 0);
}

// 64x64 tile with 512 threads: 1 load/thread.  Source pre-swizzled
// (cu ^= row&7) so swizzled ds_read_b128 is conflict-free.
__device__ __forceinline__ void stage_tile64_512(__bf16* ldsb,
                                                 const __bf16* gbase, long ldg,
                                                 int tid) {
  int row = tid >> 3, cu = tid & 7;
  const __bf16* src = gbase + (long)row * ldg + ((cu ^ (row & 7)) << 3);
  gload_lds16(src, ldsb + (long)((tid & ~63) << 3));
}

// 128x64 tile (16KB) with 512 threads: 2 loads/thread.
__device__ __forceinline__ void stage_tile128_512(__bf16* ldsb,
                                                  const __bf16* gbase,
                                                  long ldg, int tid) {
#pragma unroll
  for (int j = 0; j < 2; ++j) {
    int unit = j * 512 + tid;
    int row = unit >> 3, cu = unit & 7;
    const __bf16* src = gbase + (long)row * ldg + ((cu ^ (row & 7)) << 3);
    gload_lds16(src, ldsb + (long)((j * 512 + (tid & ~63)) << 3));
  }
}

// swizzled fragment read from a linear [R][64] tile: row r_, k-slice kk
#define RD_FRAG(ldsb, r_, kk) \
  (*(const bf16x8*)&(ldsb)[((r_) * 8 + (((kk) * 4 + l4) ^ ((r_) & 7))) * 8])

// ---------------------------------------------------------------------------
// 256x256 8-phase GEMM.  C = A * B^T.  (unchanged from rounds 8-14)
// EPI: 0 = raw bf16 (split-K partial); 1 = +bias bf16; 2 = +bias relu bf16.
// ---------------------------------------------------------------------------
#define LDA_SUB(P, MH)                                                        \
  _Pragma("unroll") for (int mi = 0; mi < 4; ++mi)                            \
  _Pragma("unroll") for (int kk = 0; kk < 2; ++kk) {                          \
    int r_ = wr + (MH) * 64 + mi * 16 + l15;                                  \
    int cu_ = kk * 4 + l4;                                                    \
    aF[mi][kk] = *(const bf16x8*)&lds[P][0][(r_ * 8 + (cu_ ^ (r_ & 7))) * 8]; \
  }

#define LDB_SUB(P, BF, NH)                                                    \
  _Pragma("unroll") for (int ni = 0; ni < 2; ++ni)                            \
  _Pragma("unroll") for (int kk = 0; kk < 2; ++kk) {                          \
    int r_ = wc + (NH) * 32 + ni * 16 + l15;                                  \
    int cu_ = kk * 4 + l4;                                                    \
    BF[ni][kk] = *(const bf16x8*)&lds[P][1][(r_ * 8 + (cu_ ^ (r_ & 7))) * 8]; \
  }

#define MFMA_Q(AF, BF, MH, NH)                                                \
  _Pragma("unroll") for (int mi = 0; mi < 4; ++mi)                            \
  _Pragma("unroll") for (int ni = 0; ni < 2; ++ni)                            \
  _Pragma("unroll") for (int kk = 0; kk < 2; ++kk)                            \
    acc[(MH) * 4 + mi][(NH) * 2 + ni] =                                       \
        __builtin_amdgcn_mfma_f32_16x16x32_bf16(                              \
            AF[mi][kk], BF[ni][kk], acc[(MH) * 4 + mi][(NH) * 2 + ni], 0, 0, 0);

#define PHASE_PRE()                                                           \
  __builtin_amdgcn_s_barrier();                                               \
  asm volatile("s_waitcnt lgkmcnt(0)" ::: "memory");                          \
  __builtin_amdgcn_sched_barrier(0);                                          \
  __builtin_amdgcn_s_setprio(1)

#define PHASE_POST()                                                          \
  __builtin_amdgcn_s_setprio(0);                                              \
  __builtin_amdgcn_sched_barrier(0);                                          \
  __builtin_amdgcn_s_barrier()

#define STAGE_A(BUFI, HF, K0)                                                 \
  do {                                                                        \
    gload_lds16(sA[HF][0] + (K0),                                             \
                &lds[BUFI][0][((HF) * 1024 + wave * 64) * 8]);                \
    gload_lds16(sA[HF][1] + (K0),                                             \
                &lds[BUFI][0][((HF) * 1024 + 512 + wave * 64) * 8]);          \
  } while (0)

#define STAGE_B(BUFI, HF, K0)                                                 \
  do {                                                                        \
    gload_lds16(sB[HF][0] + (K0),                                             \
                &lds[BUFI][1][((HF) * 1024 + wave * 64) * 8]);                \
    gload_lds16(sB[HF][1] + (K0),                                             \
                &lds[BUFI][1][((HF) * 1024 + 512 + wave * 64) * 8]);          \
  } while (0)

template <int EPI>
__global__ __launch_bounds__(512, 2) void gemm8p(
    const __bf16* __restrict__ A, const __bf16* __restrict__ Bm,
    __bf16* __restrict__ Cb, const float* __restrict__ bias, int M, int N,
    int K, int lda, int ldb, int zk, long strA, long strB, long strC,
    long strCk) {
  __shared__ __bf16 lds[2][2][256 * 64];
  const int tid = threadIdx.x;
  const int wave = tid >> 6, lane = tid & 63;
  const int l15 = lane & 15, l4 = lane >> 4;
  const int z = blockIdx.y;
  const int kc = (zk == 2) ? (z & 1) : 0;
  const int bat = (zk == 2) ? (z >> 1) : z;
  const __bf16* Ab = A + (long)bat * strA + (long)kc * K;
  const __bf16* Bb = Bm + (long)bat * strB + (long)kc * K;
  const long coff = (long)bat * strC + (long)kc * strCk;

  const int nbx = N >> 8;
  const int nwg = (M >> 8) * nbx;
  const int orig = blockIdx.x;
  const int qq = nwg >> 3, rr = nwg & 7;
  const int xcd = orig & 7, lid = orig >> 3;
  const int wg = (xcd < rr ? xcd * (qq + 1) : rr * (qq + 1) + (xcd - rr) * qq) + lid;
  const int row0 = (wg / nbx) * 256, col0 = (wg % nbx) * 256;
  const int wr = (wave >> 2) * 128;
  const int wc = (wave & 3) * 64;

  const int rsel = tid >> 3;
  const int swz = ((lane & 7) ^ (rsel & 7)) << 3;
  const __bf16* sA[2][2];
  const __bf16* sB[2][2];
#pragma unroll
  for (int hf = 0; hf < 2; ++hf)
#pragma unroll
    for (int j = 0; j < 2; ++j) {
      sA[hf][j] = Ab + (long)(row0 + hf * 128 + j * 64 + rsel) * lda + swz;
      sB[hf][j] = Bb + (long)(col0 + hf * 128 + j * 64 + rsel) * ldb + swz;
    }

  const int NT = K >> 6;
  STAGE_A(0, 0, 0);
  STAGE_A(0, 1, 0);
  STAGE_B(0, 0, 0);
  STAGE_B(0, 1, 0);
  STAGE_A(1, 0, 64);
  STAGE_B(1, 0, 64);
  STAGE_A(1, 1, 64);
  asm volatile("s_waitcnt vmcnt(6)" ::: "memory");
  __builtin_amdgcn_s_barrier();

  f32x4 acc[8][4];
#pragma unroll
  for (int i = 0; i < 8; ++i)
#pragma unroll
    for (int j = 0; j < 4; ++j) acc[i][j] = (f32x4){0.f, 0.f, 0.f, 0.f};
  bf16x8 aF[4][2], b0F[2][2], b1F[2][2];

  for (int t = 0; t < NT; ++t) {
    const int p = t & 1;
    const int kA = (t + 1 < NT ? t + 1 : NT - 1) << 6;
    const int kB = (t + 2 < NT ? t + 2 : NT - 1) << 6;
    LDA_SUB(p, 0);
    LDB_SUB(p, b0F, 0);
    STAGE_B(p ^ 1, 1, kA);
    PHASE_PRE();
    MFMA_Q(aF, b0F, 0, 0);
    PHASE_POST();
    LDB_SUB(p, b1F, 1);
    PHASE_PRE();
    MFMA_Q(aF, b1F, 0, 1);
    PHASE_POST();
    LDA_SUB(p, 1);
    STAGE_B(p, 0, kB);
    PHASE_PRE();
    MFMA_Q(aF, b0F, 1, 0);
    PHASE_POST();
    STAGE_A(p, 0, kB);
    STAGE_A(p, 1, kB);
    __builtin_amdgcn_s_barrier();
    __builtin_amdgcn_sched_barrier(0);
    __builtin_amdgcn_s_setprio(1);
    MFMA_Q(aF, b1F, 1, 1);
    __builtin_amdgcn_s_setprio(0);
    __builtin_amdgcn_sched_barrier(0);
    asm volatile("s_waitcnt vmcnt(6)" ::: "memory");
    __builtin_amdgcn_s_barrier();
  }
  asm volatile("s_waitcnt vmcnt(0)" ::: "memory");

#pragma unroll
  for (int i = 0; i < 8; ++i) {
    int row = row0 + wr + (i >> 2) * 64 + (i & 3) * 16 + l4 * 4;
#pragma unroll
    for (int j = 0; j < 4; ++j) {
      int col = col0 + wc + (j >> 1) * 32 + (j & 1) * 16 + l15;
      float bval = 0.f;
      if constexpr (EPI == 1 || EPI == 2) bval = bias[col];
#pragma unroll
      for (int r = 0; r < 4; ++r) {
        long crow = row + r;
        float v = acc[i][j][r];
        if constexpr (EPI == 1 || EPI == 2) v += bval;
        if constexpr (EPI == 2) v = fmaxf(v, 0.f);
        Cb[coff + crow * N + col] = (__bf16)v;
      }
    }
  }
}

// ---------------------------------------------------------------------------
// Attention pass A (unchanged from r14): 256 Q-rows/block, 8 waves x 32 rows.
// Q direct global->reg once per block; K streamed, vmcnt(1) dbuf.
// ---------------------------------------------------------------------------
__global__ __launch_bounds__(512, 4) void attn_stats_kernel(
    const __bf16* __restrict__ qk, float* __restrict__ sinv) {
  __shared__ __bf16 sK[2][64 * 64];
  const int tid = threadIdx.x, wave = tid >> 6, lane = tid & 63;
  const int l15 = lane & 15, l4 = lane >> 4;
  const int l0 = blockIdx.x * 256, h = blockIdx.y, b = blockIdx.z;
  const __bf16* Kb = qk + ((long)b * L_) * QKS + 1024 + h * 64;

  const __bf16* qp =
      qk + ((long)(b * L_ + l0 + wave * 32 + l15)) * QKS + h * 64 + l4 * 8;
  bf16x8 aF[2][2];
  aF[0][0] = *(const bf16x8*)qp;
  aF[0][1] = *(const bf16x8*)(qp + 32);
  aF[1][0] = *(const bf16x8*)(qp + 16 * QKS);
  aF[1][1] = *(const bf16x8*)(qp + 16 * QKS + 32);

  stage_tile64_512(sK[0], Kb, QKS, tid);
  asm volatile("s_waitcnt vmcnt(0)" ::: "memory");
  __builtin_amdgcn_s_barrier();

  float msum[2][4] = {{0.f, 0.f, 0.f, 0.f}, {0.f, 0.f, 0.f, 0.f}};
  int p = 0;
  for (int m0 = 0; m0 < 32; ++m0) {
    const int mn = (m0 + 1 < 32) ? m0 + 1 : 31;
    stage_tile64_512(sK[p ^ 1], Kb + (long)mn * 64 * QKS, QKS, tid);
    asm volatile("s_waitcnt vmcnt(1)" ::: "memory");  // buf[p] resident
    __builtin_amdgcn_s_barrier();
#pragma unroll
    for (int ni = 0; ni < 4; ++ni) {
      const int rB = ni * 16 + l15;
      bf16x8 b0 = RD_FRAG(sK[p], rB, 0);
      bf16x8 b1 = RD_FRAG(sK[p], rB, 1);
#pragma unroll
      for (int g = 0; g < 2; ++g) {
        f32x4 s = (f32x4){0.f, 0.f, 0.f, 0.f};
        s = __builtin_amdgcn_mfma_f32_16x16x32_bf16(aF[g][0], b0, s, 0, 0, 0);
        s = __builtin_amdgcn_mfma_f32_16x16x32_bf16(aF[g][1], b1, s, 0, 0, 0);
#pragma unroll
        for (int r = 0; r < 4; ++r) msum[g][r] += fexp2(s[r]);
      }
    }
    asm volatile("" ::: "memory");
    __builtin_amdgcn_s_barrier();
    p ^= 1;
  }
#pragma unroll
  for (int g = 0; g < 2; ++g) {
#pragma unroll
    for (int r = 0; r < 4; ++r) {
      float s = msum[g][r];
      for (int d = 1; d < 16; d <<= 1) s += __shfl_xor(s, d, 64);
      msum[g][r] = s;
    }
    if (l15 == 0) {
      long idx =
          ((long)(b * H_ + h)) * L_ + l0 + wave * 32 + g * 16 + l4 * 4;
      f32x4 o = {1.0f / msum[g][0], 1.0f / msum[g][1], 1.0f / msum[g][2],
                 1.0f / msum[g][3]};
      *(f32x4*)&sinv[idx] = o;
    }
  }
}

// ---------------------------------------------------------------------------
// Attention pass B (unchanged from r14): 128x128 output tile, Q+K 128-row
// LDS tiles double-buffered over h, vmcnt(4).  Emits P row-sum partials.
// ---------------------------------------------------------------------------
__global__ __launch_bounds__(512, 2) void attn_probs_kernel(
    const __bf16* __restrict__ qk, const float* __restrict__ sinv,
    const float* __restrict__ relTab, __bf16* __restrict__ P,
    float* __restrict__ rowsumT) {
  __shared__ __bf16 sQ[2][128 * 64];
  __shared__ __bf16 sKl[2][128 * 64];
  const int tid = threadIdx.x, wave = tid >> 6, lane = tid & 63;
  const int l15 = lane & 15, l4 = lane >> 4;
  const int m0 = blockIdx.x * 128, l0 = blockIdx.y * 128, b = blockIdx.z;
  const int wr2 = wave & 3, wc2 = wave >> 2;
  const __bf16* Qb = qk + ((long)(b * L_ + l0)) * QKS;
  const __bf16* Kb = qk + ((long)(b * L_ + m0)) * QKS + 1024;

  stage_tile128_512(sQ[0], Qb, QKS, tid);
  stage_tile128_512(sKl[0], Kb, QKS, tid);

  float wacc[4][8];  // [ni][fi*4+r]
#pragma unroll
  for (int i = 0; i < 4; ++i)
#pragma unroll
    for (int j = 0; j < 8; ++j) wacc[i][j] = 0.f;

  const int rA0 = wr2 * 32 + l15;
  const int rowbase = l0 + wr2 * 32 + l4 * 4;
  int p = 0;
  for (int h = 0; h < H_; ++h) {
    const int hn = (h + 1 < H_) ? h + 1 : H_ - 1;
    stage_tile128_512(sQ[p ^ 1], Qb + hn * 64, QKS, tid);
    stage_tile128_512(sKl[p ^ 1], Kb + hn * 64, QKS, tid);
    const float* svh = &sinv[((long)(b * H_ + h)) * L_];
    f32x4 iv0 = *(const f32x4*)&svh[rowbase];
    f32x4 iv1 = *(const f32x4*)&svh[rowbase + 16];
    asm volatile("s_waitcnt vmcnt(4)" ::: "memory");  // buf[p] resident
    __builtin_amdgcn_s_barrier();
    bf16x8 aF[2][2];
    aF[0][0] = RD_FRAG(sQ[p], rA0, 0);
    aF[0][1] = RD_FRAG(sQ[p], rA0, 1);
    aF[1][0] = RD_FRAG(sQ[p], rA0 + 16, 0);
    aF[1][1] = RD_FRAG(sQ[p], rA0 + 16, 1);
#pragma unroll
    for (int ni = 0; ni < 4; ++ni) {
      const int rB = wc2 * 64 + ni * 16 + l15;
      bf16x8 b0 = RD_FRAG(sKl[p], rB, 0);
      bf16x8 b1 = RD_FRAG(sKl[p], rB, 1);
#pragma unroll
      for (int fi = 0; fi < 2; ++fi) {
        f32x4 s = (f32x4){0.f, 0.f, 0.f, 0.f};
        s = __builtin_amdgcn_mfma_f32_16x16x32_bf16(aF[fi][0], b0, s, 0, 0, 0);
        s = __builtin_amdgcn_mfma_f32_16x16x32_bf16(aF[fi][1], b1, s, 0, 0, 0);
#pragma unroll
        for (int r = 0; r < 4; ++r)
          wacc[ni][fi * 4 + r] += fexp2(s[r]) * (fi ? iv1[r] : iv0[r]);
      }
    }
    asm volatile("" ::: "memory");
    __builtin_amdgcn_s_barrier();
    p ^= 1;
  }
  float rowpart[2][4] = {{0.f, 0.f, 0.f, 0.f}, {0.f, 0.f, 0.f, 0.f}};
#pragma unroll
  for (int ni = 0; ni < 4; ++ni) {
#pragma unroll
    for (int fi = 0; fi < 2; ++fi) {
#pragma unroll
      for (int r = 0; r < 4; ++r) {
        int row = rowbase + fi * 16 + r;
        int col = m0 + wc2 * 64 + ni * 16 + l15;
        float relL = relTab[row - col + 2048];  // already * log2e
        float pv = fexp2(fmaf(wacc[ni][fi * 4 + r], LOG2E_H, relL));
        P[((long)b * L_ + row) * L_ + col] = (__bf16)pv;
        rowpart[fi][r] += pv;
      }
    }
  }
#pragma unroll
  for (int fi = 0; fi < 2; ++fi) {
#pragma unroll
    for (int r = 0; r < 4; ++r) {
      float s = rowpart[fi][r];
      s += __shfl_xor(s, 1, 16);
      s += __shfl_xor(s, 2, 16);
      s += __shfl_xor(s, 4, 16);
      s += __shfl_xor(s, 8, 16);
      if (l15 == 0) {
        int row = rowbase + fi * 16 + r;
        rowsumT[((long)b * L_ + row) * 32 + (m0 >> 6) + wc2] = s;
      }
    }
  }
}

// ---------------------------------------------------------------------------
__device__ __forceinline__ void wave_reduce2(float& a, float& b) {
#pragma unroll
  for (int d = 1; d < 64; d <<= 1) {
    a += __shfl_xor(a, d, 64);
    b += __shfl_xor(b, d, 64);
  }
}

// h1 = LN(h + rinv*(p0+p1)); h2 = LN(h1).  Residual stream is bf16-only:
// hb holds h on entry, h2 on exit (same-thread read-before-write).
__global__ __launch_bounds__(256, 4) void ln12_kernel(
    __bf16* hb, const __bf16* __restrict__ p0, const __bf16* __restrict__ p1,
    const float* __restrict__ rowsumT, const float* __restrict__ w1,
    const float* __restrict__ b1, const float* __restrict__ w2,
    const float* __restrict__ b2) {
  __shared__ float sh[9];
  const int tid = threadIdx.x;
  const long row = blockIdx.x;
  const long base = row * E_ + tid * 4;
  if (tid < 32) {
    float s = rowsumT[row * 32 + tid];
#pragma unroll
    for (int d = 1; d < 32; d <<= 1) s += __shfl_xor(s, d, 32);
    if (tid == 0) sh[8] = s;
  }
  bf16x4 hv = *(const bf16x4*)&hb[base];
  bf16x4 p0v = *(const bf16x4*)&p0[base];
  bf16x4 p1v = *(const bf16x4*)&p1[base];
  __syncthreads();
  const float rinv = 1.0f / sh[8];
  float y[4];
  float s1 = 0.f, s2 = 0.f;
#pragma unroll
  for (int j = 0; j < 4; ++j) {
    y[j] = (float)hv[j] + rinv * ((float)p0v[j] + (float)p1v[j]);
    s1 += y[j];
    s2 += y[j] * y[j];
  }
  wave_reduce2(s1, s2);
  if ((tid & 63) == 0) { sh[(tid >> 6) * 2] = s1; sh[(tid >> 6) * 2 + 1] = s2; }
  __syncthreads();
  s1 = sh[0] + sh[2] + sh[4] + sh[6];
  s2 = sh[1] + sh[3] + sh[5] + sh[7];
  float mean = s1 * (1.f / E_);
  float var = s2 * (1.f / E_) - mean * mean;
  float rs = rsqrtf(var + EPS_);
  f32x4 wv = *(const f32x4*)&w1[tid * 4];
  f32x4 bv = *(const f32x4*)&b1[tid * 4];
  float h1[4];
  s1 = 0.f; s2 = 0.f;
#pragma unroll
  for (int j = 0; j < 4; ++j) {
    h1[j] = (y[j] - mean) * rs * wv[j] + bv[j];
    s1 += h1[j];
    s2 += h1[j] * h1[j];
  }
  __syncthreads();
  wave_reduce2(s1, s2);
  if ((tid & 63) == 0) { sh[(tid >> 6) * 2] = s1; sh[(tid >> 6) * 2 + 1] = s2; }
  __syncthreads();
  s1 = sh[0] + sh[2] + sh[4] + sh[6];
  s2 = sh[1] + sh[3] + sh[5] + sh[7];
  mean = s1 * (1.f / E_);
  var = s2 * (1.f / E_) - mean * mean;
  rs = rsqrtf(var + EPS_);
  wv = *(const f32x4*)&w2[tid * 4];
  bv = *(const f32x4*)&b2[tid * 4];
  bf16x4 ob;
#pragma unroll
  for (int j = 0; j < 4; ++j)
    ob[j] = (__bf16)((h1[j] - mean) * rs * wv[j] + bv[j]);
  *(bf16x4*)&hb[base] = ob;
}

// out = LN(h2 + (p0+p1+b2)).  hb holds h2 on entry, new h (bf16) on exit;
// outf (f32) written only when non-null (final layer -> d_out).
__global__ __launch_bounds__(256, 4) void ln3_kernel(
    __bf16* hb, const __bf16* __restrict__ p0, const __bf16* __restrict__ p1,
    const float* __restrict__ bias2, const float* __restrict__ w3,
    const float* __restrict__ b3, float* __restrict__ outf) {
  __shared__ float sh[8];
  const int tid = threadIdx.x;
  const long row = blockIdx.x;
  const long base = row * E_ + tid * 4;
  bf16x4 hv = *(const bf16x4*)&hb[base];
  bf16x4 p0v = *(const bf16x4*)&p0[base];
  bf16x4 p1v = *(const bf16x4*)&p1[base];
  f32x4 b2v = *(const f32x4*)&bias2[tid * 4];
  float y[4];
  float s1 = 0.f, s2 = 0.f;
#pragma unroll
  for (int j = 0; j < 4; ++j) {
    y[j] = (float)hv[j] + (float)p0v[j] + (float)p1v[j] + b2v[j];
    s1 += y[j];
    s2 += y[j] * y[j];
  }
  wave_reduce2(s1, s2);
  if ((tid & 63) == 0) { sh[(tid >> 6) * 2] = s1; sh[(tid >> 6) * 2 + 1] = s2; }
  __syncthreads();
  s1 = sh[0] + sh[2] + sh[4] + sh[6];
  s2 = sh[1] + sh[3] + sh[5] + sh[7];
  float mean = s1 * (1.f / E_);
  float var = s2 * (1.f / E_) - mean * mean;
  float rs = rsqrtf(var + EPS_);
  f32x4 wv = *(const f32x4*)&w3[tid * 4];
  f32x4 bv = *(const f32x4*)&b3[tid * 4];
  f32x4 o;
  bf16x4 ob;
#pragma unroll
  for (int j = 0; j < 4; ++j) {
    float v = (y[j] - mean) * rs * wv[j] + bv[j];
    o[j] = v;
    ob[j] = (__bf16)v;
  }
  *(bf16x4*)&hb[base] = ob;
  if (outf) *(f32x4*)&outf[base] = o;
}

// ---------------------------------------------------------------------------
__global__ __launch_bounds__(256, 4) void transpose_kernel(
    const __bf16* __restrict__ X, __bf16* __restrict__ XT) {
  __shared__ __bf16 t[64 * 66];
  const int l0 = blockIdx.x * 64, e0 = blockIdx.y * 64, b = blockIdx.z;
  const int tid = threadIdx.x;
#pragma unroll
  for (int r = 0; r < 2; ++r) {
    int c = tid + 256 * r;
    int rw = c >> 3, c8 = (c & 7) * 8;
    *(bf16x8*)&t[rw * 66 + c8] =
        *(const bf16x8*)&X[((long)(b * L_) + l0 + rw) * E_ + e0 + c8];
  }
  __syncthreads();
#pragma unroll
  for (int r = 0; r < 2; ++r) {
    int c = tid + 256 * r;
    int er = c >> 3, l8 = (c & 7) * 8;
    bf16x8 v;
#pragma unroll
    for (int j = 0; j < 8; ++j) v[j] = t[(l8 + j) * 66 + er];
    *(bf16x8*)&XT[((long)(b * E_) + e0 + er) * L_ + l0 + l8] = v;
  }
}

__global__ __launch_bounds__(256, 4) void f32_to_bf16_kernel(
    const float* __restrict__ x, __bf16* __restrict__ y) {
  long i = ((long)blockIdx.x * 256 + threadIdx.x) * 4;
  f32x4 v = *(const f32x4*)&x[i];
  bf16x4 o;
#pragma unroll
  for (int j = 0; j < 4; ++j) o[j] = (__bf16)v[j];
  *(bf16x4*)&y[i] = o;
}

// fused [D][2048][1024] Wqk (rows 0-1023 = Wq * EXPSC, 1024-2047 = Wk), bf16
__global__ __launch_bounds__(256, 4) void build_wqk_kernel(
    const float* __restrict__ Wq, const float* __restrict__ Wk,
    __bf16* __restrict__ out) {
  long i = ((long)blockIdx.x * 256 + threadIdx.x) * 4;
  long d = i >> 21;
  long rem = i & ((1L << 21) - 1);
  long row = rem >> 10, col = rem & 1023;
  const bool isQ = (row < 1024);
  const float* src = isQ ? &Wq[(d << 20) + (row << 10) + col]
                         : &Wk[(d << 20) + ((row - 1024) << 10) + col];
  const float sc = isQ ? EXPSC : 1.0f;
  f32x4 v = *(const f32x4*)src;
  bf16x4 o;
#pragma unroll
  for (int j = 0; j < 4; ++j) o[j] = (__bf16)(v[j] * sc);
  *(bf16x4*)&out[i] = o;
}

__global__ __launch_bounds__(256, 4) void build_bqk_kernel(
    const float* __restrict__ bq, const float* __restrict__ bk,
    float* __restrict__ out) {
  int i = blockIdx.x * 256 + threadIdx.x;  // D*2048
  int d = i >> 11, c = i & 2047;
  out[i] = (c < 1024) ? bq[d * 1024 + c] * EXPSC : bk[d * 1024 + c - 1024];
}

// relTab[d+2048] = exp(-|d|/16) * log2(e)
__global__ __launch_bounds__(256, 4) void build_rel_kernel(
    float* __restrict__ relTab) {
  int i = blockIdx.x * 256 + threadIdx.x;  // 4096
  relTab[i] = __expf(-fabsf((float)(i - 2048)) * (1.0f / 16.0f)) * LOG2E;
}

// ---------------------------------------------------------------------------
extern "C" void kernel_launch(void* const* d_in, const int* in_sizes, int n_in,
                              void* d_out, int out_size, void* d_ws,
                              size_t ws_size, hipStream_t stream) {
  const float* x = (const float*)d_in[0];
  const float* Wq = (const float*)d_in[1];
  const float* Wk = (const float*)d_in[2];
  const float* bq = (const float*)d_in[3];
  const float* bk = (const float*)d_in[4];
  const float* l1w = (const float*)d_in[5];
  const float* l1b = (const float*)d_in[6];
  const float* l2w = (const float*)d_in[7];
  const float* l2b = (const float*)d_in[8];
  const float* l3w = (const float*)d_in[9];
  const float* l3b = (const float*)d_in[10];
  const float* W1 = (const float*)d_in[11];
  const float* b1 = (const float*)d_in[12];
  const float* W2 = (const float*)d_in[13];
  const float* b2 = (const float*)d_in[14];

  char* p = (char*)d_ws;
  auto take = [&](size_t bytes) -> char* {
    char* r = p;
    p += (bytes + 255) & ~(size_t)255;
    return r;
  };
  __bf16* wqk_bf = (__bf16*)take((size_t)D_ * 2048 * 1024 * 2);
  __bf16* w1_bf = (__bf16*)take((size_t)D_ * F_ * E_ * 2);
  __bf16* w2_bf = (__bf16*)take((size_t)D_ * E_ * F_ * 2);
  __bf16* h_bf = (__bf16*)take((size_t)BL_ * E_ * 2);
  __bf16* hT = (__bf16*)take((size_t)BL_ * E_ * 2);
  __bf16* qk_bf = (__bf16*)take((size_t)BL_ * QKS * 2);     // union with ffmid
  __bf16* Pbuf = (__bf16*)take((size_t)B_ * L_ * L_ * 2);   // union with ffmid
  __bf16* ffmid = qk_bf;  // [BL][F] bf16 == qk+P exactly
  float* bqk = (float*)take((size_t)D_ * 2048 * 4);
  float* relTab = (float*)take((size_t)4096 * 4);
  float* sinv = (float*)take((size_t)B_ * H_ * L_ * 4);
  float* rowsumT = (float*)take((size_t)BL_ * 32 * 4);
  __bf16* partB = (__bf16*)take((size_t)2 * BL_ * E_ * 2);  // bf16 partials
  __bf16* part0 = partB;
  __bf16* part1 = partB + (size_t)BL_ * E_;

  // --- setup ---
  build_wqk_kernel<<<D_ * 2048 * 1024 / 1024, 256, 0, stream>>>(Wq, Wk, wqk_bf);
  build_bqk_kernel<<<D_ * 2048 / 256, 256, 0, stream>>>(bq, bk, bqk);
  build_rel_kernel<<<16, 256, 0, stream>>>(relTab);
  f32_to_bf16_kernel<<<D_ * F_ * E_ / 1024, 256, 0, stream>>>(W1, w1_bf);
  f32_to_bf16_kernel<<<D_ * E_ * F_ / 1024, 256, 0, stream>>>(W2, w2_bf);
  f32_to_bf16_kernel<<<BL_ * E_ / 1024, 256, 0, stream>>>(x, h_bf);
  transpose_kernel<<<dim3(L_ / 64, E_ / 64, B_), 256, 0, stream>>>(h_bf, hT);

  for (int d = 0; d < D_; ++d) {
    // fused QK projection: [BL][2048] = h @ [Wq*c;Wk]^T + [bq*c;bk]  (256 wgs)
    gemm8p<1><<<dim3(256, 1), 512, 0, stream>>>(
        h_bf, wqk_bf + (size_t)d * 2048 * 1024, qk_bf, bqk + d * 2048, BL_,
        2048, E_, E_, E_, 1, 0, 0, 0, 0);
    attn_stats_kernel<<<dim3(L_ / 256, H_, B_), 512, 0, stream>>>(qk_bf, sinv);
    attn_probs_kernel<<<dim3(L_ / 128, L_ / 128, B_), 512, 0, stream>>>(
        qk_bf, sinv, relTab, Pbuf, rowsumT);
    // sa-partials = P @ h  (4 batches x split-K2 = 8 z -> 256 wgs, bf16 out)
    gemm8p<0><<<dim3(32, 8), 512, 0, stream>>>(
        Pbuf, hT, partB, nullptr, L_, E_, L_ / 2, L_, L_, 2, (long)L_ * L_,
        (long)E_ * L_, (long)L_ * E_, (long)BL_ * E_);
    // h (bf16, in h_bf) -> h2 (bf16, in h_bf)
    ln12_kernel<<<BL_, 256, 0, stream>>>(h_bf, part0, part1, rowsumT,
                                         l1w + d * E_, l1b + d * E_,
                                         l2w + d * E_, l2b + d * E_);
    // FFN1 (512 wgs)
    gemm8p<2><<<dim3(512, 1), 512, 0, stream>>>(
        h_bf, w1_bf + (size_t)d * F_ * E_, ffmid, b1 + d * F_, BL_, F_, E_,
        E_, E_, 1, 0, 0, 0, 0);
    // FFN2 partials (split-K2 -> 256 wgs, bf16 out)
    gemm8p<0><<<dim3(128, 2), 512, 0, stream>>>(
        ffmid, w2_bf + (size_t)d * E_ * F_, partB, nullptr, BL_, E_, F_ / 2,
        F_, F_, 2, 0, 0, 0, (long)BL_ * E_);
    // h2 (h_bf) -> new h (h_bf); f32 out only on final layer
    float* outp = (d == D_ - 1) ? (float*)d_out : nullptr;
    ln3_kernel<<<BL_, 256, 0, stream>>>(h_bf, part0, part1, b2 + d * E_,
                                        l3w + d * E_, l3b + d * E_, outp);
    if (d < D_ - 1) {
      transpose_kernel<<<dim3(L_ / 64, E_ / 64, B_), 256, 0, stream>>>(h_bf, hT);
    }
  }
}